// Round 2
// baseline (445.792 us; speedup 1.0000x reference)
//
#include <hip/hip_runtime.h>

typedef _Float16 f16;
typedef _Float16 f16x4 __attribute__((ext_vector_type(4)));
typedef _Float16 f16x8 __attribute__((ext_vector_type(8)));
typedef float f32x4 __attribute__((ext_vector_type(4)));

#define DEV static __device__ __forceinline__

DEV void gl_lds16(const void* g, void* l) {
  __builtin_amdgcn_global_load_lds(
      (const __attribute__((address_space(1))) void*)g,
      (__attribute__((address_space(3))) void*)l, 16, 0, 0);
}

// ---------------- 1) cast fp32 -> fp16 (x + 4 weights) ----------------
__global__ void cast_f16_kernel(const float* __restrict__ x,
                                const float* __restrict__ w0,
                                const float* __restrict__ w1,
                                const float* __restrict__ w2,
                                const float* __restrict__ w3,
                                f16* __restrict__ xb, f16* __restrict__ b0,
                                f16* __restrict__ b1, f16* __restrict__ b2,
                                f16* __restrict__ b3) {
  const int total4 = (8388608 + 4 * 4194304) / 4;
  for (int i = blockIdx.x * blockDim.x + threadIdx.x; i < total4;
       i += gridDim.x * blockDim.x) {
    int e = i << 2;
    const float* s; f16* d; int off;
    if (e < 8388608)        { s = x;  d = xb; off = e; }
    else if (e < 12582912)  { s = w0; d = b0; off = e - 8388608; }
    else if (e < 16777216)  { s = w1; d = b1; off = e - 12582912; }
    else if (e < 20971520)  { s = w2; d = b2; off = e - 16777216; }
    else                    { s = w3; d = b3; off = e - 20971520; }
    float4 v = *(const float4*)(s + off);
    f16x4 hv = {(f16)v.x, (f16)v.y, (f16)v.z, (f16)v.w};
    *(f16x4*)(d + off) = hv;
  }
}

// ---------------- 2a) la[nm][m][r] = x @ A_nm  (fp32, q/k/v) ----------------
__global__ __launch_bounds__(256) void lora_x_kernel(
    const float* __restrict__ x, const float* __restrict__ Aq,
    const float* __restrict__ Ak, const float* __restrict__ Av,
    float* __restrict__ la) {
  const int wave = threadIdx.x >> 6, lane = threadIdx.x & 63;
  const int m = blockIdx.x * 4 + wave;
  const float* xrow = x + (size_t)m * 2048;
  const float* As[3] = {Aq, Ak, Av};
  float acc[3][8] = {};
  for (int i = 0; i < 32; ++i) {
    int k = i * 64 + lane;
    float xv = xrow[k];
#pragma unroll
    for (int nm = 0; nm < 3; ++nm) {
      const float4* ap = (const float4*)(As[nm] + (size_t)k * 8);
      float4 a0 = ap[0], a1 = ap[1];
      acc[nm][0] += xv * a0.x; acc[nm][1] += xv * a0.y;
      acc[nm][2] += xv * a0.z; acc[nm][3] += xv * a0.w;
      acc[nm][4] += xv * a1.x; acc[nm][5] += xv * a1.y;
      acc[nm][6] += xv * a1.z; acc[nm][7] += xv * a1.w;
    }
  }
#pragma unroll
  for (int nm = 0; nm < 3; ++nm)
#pragma unroll
    for (int r = 0; r < 8; ++r) {
      float v = acc[nm][r];
#pragma unroll
      for (int off = 1; off < 64; off <<= 1) v += __shfl_xor(v, off);
      acc[nm][r] = v;
    }
  if (lane == 0) {
#pragma unroll
    for (int nm = 0; nm < 3; ++nm)
#pragma unroll
      for (int r = 0; r < 8; ++r)
        la[nm * 32768 + (size_t)m * 8 + r] = acc[nm][r];
  }
}

// ---------------- 2b) lap[m][r] = y @ p_A  (y = f16 attention output) -------
__global__ __launch_bounds__(256) void lora_p_kernel(
    const f16* __restrict__ y, const float* __restrict__ Ap,
    float* __restrict__ lap) {
  const int wave = threadIdx.x >> 6, lane = threadIdx.x & 63;
  const int m = blockIdx.x * 4 + wave;
  const f16* yrow = y + (size_t)m * 2048;
  float acc[8] = {};
  for (int i = 0; i < 4; ++i) {
    int k0 = i * 512 + lane * 8;
    f16x8 yv = *(const f16x8*)(yrow + k0);
#pragma unroll
    for (int j = 0; j < 8; ++j) {
      float xv = (float)yv[j];
      const float4* ap = (const float4*)(Ap + (size_t)(k0 + j) * 8);
      float4 a0 = ap[0], a1 = ap[1];
      acc[0] += xv * a0.x; acc[1] += xv * a0.y;
      acc[2] += xv * a0.z; acc[3] += xv * a0.w;
      acc[4] += xv * a1.x; acc[5] += xv * a1.y;
      acc[6] += xv * a1.z; acc[7] += xv * a1.w;
    }
  }
#pragma unroll
  for (int r = 0; r < 8; ++r) {
    float v = acc[r];
#pragma unroll
    for (int off = 1; off < 64; off <<= 1) v += __shfl_xor(v, off);
    acc[r] = v;
  }
  if (lane == 0) {
#pragma unroll
    for (int r = 0; r < 8; ++r) lap[(size_t)m * 8 + r] = acc[r];
  }
}

// ---------------- 3/6) MFMA GEMM: C = A(f16) @ W^T + b + la@Bm ----------------
// MODE 0: rope epilogue -> f16 [B,H,T,D]   (q,k; N-tile==one head)
// MODE 1: plain f16 [B,T,C]                (v)
// MODE 2: fp32 [B,T,C]                     (p -> d_out)
template <int MODE>
__global__ __launch_bounds__(256, 2) void gemm_kernel(
    const f16* __restrict__ A, const f16* __restrict__ Bw,
    const float* __restrict__ bias, const float* __restrict__ la,
    const float* __restrict__ Bm, const int* __restrict__ use_lora,
    const float* __restrict__ cosT, const float* __restrict__ sinT,
    void* __restrict__ out) {
  __shared__ char smem[32768];
  const int tid = threadIdx.x;
  const int wave = tid >> 6, lane = tid & 63;
  const int lr = lane & 15, lg = lane >> 4;
  const int bm = blockIdx.x >> 4, bn = blockIdx.x & 15;
  const int m0 = bm << 7, n0 = bn << 7;
  const int wr = wave >> 1, wc = wave & 1;

  // staging: LDS linear dest, pre-swizzled global source (XOR (row&7)<<4)
  uint aoff[4], boff[4];
#pragma unroll
  for (int r = 0; r < 4; ++r) {
    uint beta = (uint)(wave * 4 + r) * 1024 + (uint)lane * 16;
    uint row = beta >> 7;
    uint c = (beta & 127u) ^ ((row & 7u) << 4);
    aoff[r] = (uint)(m0 + row) * 4096 + c;
    boff[r] = (uint)(n0 + row) * 4096 + c;
  }
  const char* Ab = (const char*)A;
  const char* Bb = (const char*)Bw;

  f32x4 acc[4][4] = {};

  for (int kt = 0; kt < 32; ++kt) {
    __syncthreads();
    const int kb = kt << 7;
#pragma unroll
    for (int r = 0; r < 4; ++r) {
      gl_lds16(Ab + (size_t)(aoff[r] + kb), smem + (wave * 4 + r) * 1024);
      gl_lds16(Bb + (size_t)(boff[r] + kb), smem + 16384 + (wave * 4 + r) * 1024);
    }
    __syncthreads();

    f16x8 af[2][4], bf[2][4];
#pragma unroll
    for (int ks = 0; ks < 2; ++ks) {
#pragma unroll
      for (int mi = 0; mi < 4; ++mi) {
        int row = wr * 64 + mi * 16 + lr;
        int c = (ks * 64 + lg * 16) ^ ((row & 7) << 4);
        af[ks][mi] = *(const f16x8*)(smem + row * 128 + c);
      }
#pragma unroll
      for (int ni = 0; ni < 4; ++ni) {
        int row = wc * 64 + ni * 16 + lr;
        int c = (ks * 64 + lg * 16) ^ ((row & 7) << 4);
        bf[ks][ni] = *(const f16x8*)(smem + 16384 + row * 128 + c);
      }
    }
#pragma unroll
    for (int ks = 0; ks < 2; ++ks)
#pragma unroll
      for (int mi = 0; mi < 4; ++mi)
#pragma unroll
        for (int ni = 0; ni < 4; ++ni)
          acc[mi][ni] = __builtin_amdgcn_mfma_f32_16x16x32_f16(
              af[ks][mi], bf[ks][ni], acc[mi][ni], 0, 0, 0);
  }

  const int ul = use_lora[0];
  __syncthreads();  // smem reuse for output staging (MODE<2)

  float bv[4], bml[4][8];
#pragma unroll
  for (int ni = 0; ni < 4; ++ni) {
    int n = n0 + wc * 64 + ni * 16 + lr;
    bv[ni] = bias[n];
    if (ul) {
#pragma unroll
      for (int r = 0; r < 8; ++r) bml[ni][r] = Bm[r * 2048 + n];
    }
  }

  f16* stg = (f16*)smem;
#pragma unroll
  for (int mi = 0; mi < 4; ++mi) {
    const int mbase = m0 + wr * 64 + mi * 16 + lg * 4;
    float lar[4][8];
    if (ul) {
#pragma unroll
      for (int rg = 0; rg < 4; ++rg) {
        const float4* lp = (const float4*)(la + (size_t)(mbase + rg) * 8);
        float4 l0 = lp[0], l1 = lp[1];
        lar[rg][0] = l0.x; lar[rg][1] = l0.y; lar[rg][2] = l0.z; lar[rg][3] = l0.w;
        lar[rg][4] = l1.x; lar[rg][5] = l1.y; lar[rg][6] = l1.z; lar[rg][7] = l1.w;
      }
    }
#pragma unroll
    for (int ni = 0; ni < 4; ++ni) {
      const int n = n0 + wc * 64 + ni * 16 + lr;
#pragma unroll
      for (int rg = 0; rg < 4; ++rg) {
        float v = acc[mi][ni][rg] + bv[ni];
        if (ul) {
#pragma unroll
          for (int r = 0; r < 8; ++r) v += lar[rg][r] * bml[ni][r];
        }
        if (MODE == 0) {
          float pv = __shfl_xor(v, 1);  // partner column (RoPE pair)
          const int m = mbase + rg;
          const int t = m & 2047;
          const int d = n & 127;
          const int ci = t * 64 + (d >> 1);
          float cs = cosT[ci], sn = sinT[ci];
          float res = ((lane & 1) == 0) ? (v * cs - pv * sn)
                                        : (pv * sn + v * cs);
          stg[(wr * 64 + mi * 16 + lg * 4 + rg) * 128 +
              (wc * 64 + ni * 16 + lr)] = (f16)res;
        } else if (MODE == 1) {
          stg[(wr * 64 + mi * 16 + lg * 4 + rg) * 128 +
              (wc * 64 + ni * 16 + lr)] = (f16)v;
        } else {
          ((float*)out)[(size_t)(mbase + rg) * 2048 + n] = v;
        }
      }
    }
  }

  if (MODE < 2) {
    __syncthreads();
    if (MODE == 0) {
      // tile cols n0..n0+127 == head bn fully; rows -> (b,t)
      const long b_ = m0 >> 11;
      const int tb = m0 & 2047;
      char* obase = (char*)out + ((b_ * 16 + bn) * 2048 + tb) * 256;
#pragma unroll
      for (int p = 0; p < 8; ++p) {
        int s = p * 4096 + tid * 16;
        int row = s >> 8, c = s & 255;
        *(uint4*)(obase + (long)row * 256 + c) = *(const uint4*)(smem + s);
      }
    } else {
      char* obase = (char*)out + ((long)m0 * 2048 + n0) * 2;
#pragma unroll
      for (int p = 0; p < 8; ++p) {
        int s = p * 4096 + tid * 16;
        int row = s >> 8, c = s & 255;
        *(uint4*)(obase + (long)row * 4096 + c) = *(const uint4*)(smem + s);
      }
    }
  }
}

// ---------------- 4) v [B,T,H,D] -> vt [B,H,D,T] ----------------
__global__ void transpose_v_kernel(const ushort* __restrict__ vbi,
                                   ushort* __restrict__ vto) {
  __shared__ ushort tile[32][33];
  const int t0 = blockIdx.x << 5;
  const int d0 = blockIdx.y << 5;
  const int bh = blockIdx.z;
  const int b = bh >> 4, h = bh & 15;
  const int tx = threadIdx.x, ty = threadIdx.y;
  const ushort* src = vbi + ((size_t)(b * 2048 + t0)) * 2048 + h * 128 + d0;
#pragma unroll
  for (int i = 0; i < 4; ++i)
    tile[ty + 8 * i][tx] = src[(size_t)(ty + 8 * i) * 2048 + tx];
  __syncthreads();
  ushort* dst = vto + ((size_t)bh * 128 + d0) * 2048 + t0;
#pragma unroll
  for (int i = 0; i < 4; ++i)
    dst[(size_t)(ty + 8 * i) * 2048 + tx] = tile[tx][ty + 8 * i];
}

// ---------------- 5) causal flash attention ----------------
// block: 4 waves, 64 q-rows per block, KV tiles of 64.
__global__ __launch_bounds__(256, 2) void attn_kernel(
    const f16* __restrict__ qr, const f16* __restrict__ kr,
    const f16* __restrict__ vt, f16* __restrict__ y) {
  __shared__ char smem[41984];
  char* Ks = smem;            // 64 x 256B (xor-swizzled)
  char* Vs = smem + 16384;    // 128 x 128B (xor-swizzled)
  char* Ps = smem + 32768;    // 64 x 144B (padded)
  const int tid = threadIdx.x, wave = tid >> 6, lane = tid & 63;
  const int lr = lane & 15, lg = lane >> 4;
  const int q0 = blockIdx.x << 6;
  const int h = blockIdx.y, b = blockIdx.z;
  const long bh = b * 16 + h;

  const char* qbase = (const char*)qr + (bh * 2048 + q0 + wave * 16 + lr) * 256;
  f16x8 qf[4];
#pragma unroll
  for (int ks = 0; ks < 4; ++ks)
    qf[ks] = *(const f16x8*)(qbase + ks * 64 + lg * 16);

  f32x4 o[8] = {};
  float mrow[4] = {-3e38f, -3e38f, -3e38f, -3e38f};
  float lsum[4] = {};

  const char* kbase = (const char*)kr + bh * 2048 * 256;
  const char* vbase = (const char*)vt + bh * 128 * 4096;
  const float SC2 = 0.12752551286084103f;  // (1/sqrt(128))*log2(e)
  const int ktmax = blockIdx.x;

  for (int kt = 0; kt <= ktmax; ++kt) {
    const int kv0 = kt << 6;
    __syncthreads();
#pragma unroll
    for (int r = 0; r < 4; ++r) {
      uint s = (uint)(wave * 4 + r) * 1024 + (uint)lane * 16;
      {
        uint row = s >> 8, c = (s & 255u) ^ ((row & 7u) << 4);
        gl_lds16(kbase + (size_t)(kv0 + row) * 256 + c,
                 Ks + (wave * 4 + r) * 1024);
      }
      {
        uint row = s >> 7, c = (s & 127u) ^ ((row & 7u) << 4);
        gl_lds16(vbase + (size_t)row * 4096 + kv0 * 2 + c,
                 Vs + (wave * 4 + r) * 1024);
      }
    }
    __syncthreads();

    f32x4 sa[4] = {};
#pragma unroll
    for (int ks = 0; ks < 4; ++ks)
#pragma unroll
      for (int n = 0; n < 4; ++n) {
        int row = n * 16 + lr;
        int c = (ks * 64 + lg * 16) ^ ((row & 7) << 4);
        f16x8 kf = *(const f16x8*)(Ks + row * 256 + c);
        sa[n] = __builtin_amdgcn_mfma_f32_16x16x32_f16(qf[ks], kf, sa[n], 0, 0, 0);
      }

    float L[4][4];
    float pm[4] = {-3e38f, -3e38f, -3e38f, -3e38f};
    const bool diag = (kt == ktmax);
#pragma unroll
    for (int n = 0; n < 4; ++n)
#pragma unroll
      for (int rg = 0; rg < 4; ++rg) {
        float Lv = sa[n][rg] * SC2;
        if (diag) {
          int qa = q0 + wave * 16 + lg * 4 + rg;
          int ka = kv0 + n * 16 + lr;
          if (ka > qa) Lv = -3e37f;
        }
        L[n][rg] = Lv;
        pm[rg] = fmaxf(pm[rg], Lv);
      }
#pragma unroll
    for (int rg = 0; rg < 4; ++rg)
#pragma unroll
      for (int off = 1; off < 16; off <<= 1)
        pm[rg] = fmaxf(pm[rg], __shfl_xor(pm[rg], off));

    float alpha[4], ps[4];
#pragma unroll
    for (int rg = 0; rg < 4; ++rg) {
      float mn = fmaxf(mrow[rg], pm[rg]);
      alpha[rg] = exp2f(mrow[rg] - mn);
      mrow[rg] = mn;
      ps[rg] = 0.f;
    }
#pragma unroll
    for (int n = 0; n < 4; ++n)
#pragma unroll
      for (int rg = 0; rg < 4; ++rg) {
        float p = exp2f(L[n][rg] - mrow[rg]);
        ps[rg] += p;
        *(f16*)(Ps + (wave * 16 + lg * 4 + rg) * 144 + (n * 16 + lr) * 2) = (f16)p;
      }
#pragma unroll
    for (int rg = 0; rg < 4; ++rg) {
#pragma unroll
      for (int off = 1; off < 16; off <<= 1) ps[rg] += __shfl_xor(ps[rg], off);
      lsum[rg] = lsum[rg] * alpha[rg] + ps[rg];
    }
#pragma unroll
    for (int dt = 0; dt < 8; ++dt)
#pragma unroll
      for (int rg = 0; rg < 4; ++rg) o[dt][rg] *= alpha[rg];

#pragma unroll
    for (int ks2 = 0; ks2 < 2; ++ks2) {
      f16x8 pf = *(const f16x8*)(Ps + (wave * 16 + lr) * 144 + ks2 * 64 + lg * 16);
#pragma unroll
      for (int dt = 0; dt < 8; ++dt) {
        int drow = dt * 16 + lr;
        int c = (ks2 * 64 + lg * 16) ^ ((drow & 7) << 4);
        f16x8 vf = *(const f16x8*)(Vs + drow * 128 + c);
        o[dt] = __builtin_amdgcn_mfma_f32_16x16x32_f16(pf, vf, o[dt], 0, 0, 0);
      }
    }
  }

  // epilogue: normalize, stage in LDS, coalesced store to y [B,T,C]
  __syncthreads();
  f16* Os = (f16*)smem;
#pragma unroll
  for (int dt = 0; dt < 8; ++dt)
#pragma unroll
    for (int rg = 0; rg < 4; ++rg)
      Os[(wave * 16 + lg * 4 + rg) * 128 + dt * 16 + lr] =
          (f16)(o[dt][rg] / lsum[rg]);
  __syncthreads();
#pragma unroll
  for (int p = 0; p < 4; ++p) {
    int s = p * 4096 + tid * 16;
    int row = s >> 8, c = s & 255;
    char* dst = (char*)y + ((long)(b * 2048 + q0 + row) * 2048 + h * 128) * 2 + c;
    *(uint4*)dst = *(const uint4*)(smem + s);
  }
}

// ---------------- launch ----------------
extern "C" void kernel_launch(void* const* d_in, const int* in_sizes, int n_in,
                              void* d_out, int out_size, void* d_ws,
                              size_t ws_size, hipStream_t stream) {
  (void)in_sizes; (void)n_in; (void)out_size; (void)ws_size;
  const float* x   = (const float*)d_in[0];
  const float* q_w = (const float*)d_in[1];
  const float* q_b = (const float*)d_in[2];
  const float* q_A = (const float*)d_in[3];
  const float* q_B = (const float*)d_in[4];
  const float* k_w = (const float*)d_in[5];
  const float* k_b = (const float*)d_in[6];
  const float* k_A = (const float*)d_in[7];
  const float* k_B = (const float*)d_in[8];
  const float* v_w = (const float*)d_in[9];
  const float* v_b = (const float*)d_in[10];
  const float* v_A = (const float*)d_in[11];
  const float* v_B = (const float*)d_in[12];
  const float* p_w = (const float*)d_in[13];
  const float* p_b = (const float*)d_in[14];
  const float* p_A = (const float*)d_in[15];
  const float* p_B = (const float*)d_in[16];
  const float* cosT = (const float*)d_in[17];
  const float* sinT = (const float*)d_in[18];
  const int* use_lora = (const int*)d_in[20];  // mask (19) implicit: causal

  char* ws = (char*)d_ws;
  f16* xb  = (f16*)(ws);                    // 16.78 MB ; later reused as vt
  f16* wqb = (f16*)(ws + 16777216);
  f16* wkb = (f16*)(ws + 25165824);
  f16* wvb = (f16*)(ws + 33554432);
  f16* wpb = (f16*)(ws + 41943040);
  float* la = (float*)(ws + 50331648);      // [4][4096][8] fp32
  f16* qr  = (f16*)(ws + 50855936);         // [B,H,T,D]
  f16* kr  = (f16*)(ws + 67633152);         // [B,H,T,D]
  f16* vb  = (f16*)(ws + 84410368);         // [B,T,C] ; later reused as y
  f16* vt  = (f16*)(ws);                    // [B,H,D,T] aliases xb (xb dead)
  f16* y   = vb;                            // aliases vb (vb dead after transpose)
  float* lap = la + 98304;                  // p-slot, filled from y post-attn

  cast_f16_kernel<<<dim3(2048), dim3(256), 0, stream>>>(
      x, q_w, k_w, v_w, p_w, xb, wqb, wkb, wvb, wpb);
  lora_x_kernel<<<dim3(1024), dim3(256), 0, stream>>>(x, q_A, k_A, v_A, la);
  gemm_kernel<0><<<dim3(512), dim3(256), 0, stream>>>(
      xb, wqb, q_b, la, q_B, use_lora, cosT, sinT, (void*)qr);
  gemm_kernel<0><<<dim3(512), dim3(256), 0, stream>>>(
      xb, wkb, k_b, la + 32768, k_B, use_lora, cosT, sinT, (void*)kr);
  gemm_kernel<1><<<dim3(512), dim3(256), 0, stream>>>(
      xb, wvb, v_b, la + 65536, v_B, use_lora, nullptr, nullptr, (void*)vb);
  transpose_v_kernel<<<dim3(64, 4, 32), dim3(32, 8), 0, stream>>>(
      (const ushort*)vb, (ushort*)vt);
  attn_kernel<<<dim3(32, 16, 2), dim3(256), 0, stream>>>(qr, kr, vt, y);
  lora_p_kernel<<<dim3(1024), dim3(256), 0, stream>>>(y, p_A, lap);
  gemm_kernel<2><<<dim3(512), dim3(256), 0, stream>>>(
      y, wpb, p_b, lap, p_B, use_lora, nullptr, nullptr, d_out);
}

// Round 4
// 399.032 us; speedup vs baseline: 1.1172x; 1.1172x over previous
//
#include <hip/hip_runtime.h>

typedef _Float16 f16;
typedef _Float16 f16x4 __attribute__((ext_vector_type(4)));
typedef _Float16 f16x8 __attribute__((ext_vector_type(8)));
typedef __fp16 hf2 __attribute__((ext_vector_type(2)));
typedef float f32x4 __attribute__((ext_vector_type(4)));

#define DEV static __device__ __forceinline__

DEV void gl_lds16(const void* g, void* l) {
  __builtin_amdgcn_global_load_lds(
      (const __attribute__((address_space(1))) void*)g,
      (__attribute__((address_space(3))) void*)l, 16, 0, 0);
}

DEV uint pkrtz(float a, float b) {
  hf2 h = __builtin_amdgcn_cvt_pkrtz(a, b);
  return __builtin_bit_cast(uint, h);
}

// ---------------- 1) cast fp32 -> fp16 (x + 4 weights) ----------------
__global__ void cast_f16_kernel(const float* __restrict__ x,
                                const float* __restrict__ w0,
                                const float* __restrict__ w1,
                                const float* __restrict__ w2,
                                const float* __restrict__ w3,
                                f16* __restrict__ xb, f16* __restrict__ b0,
                                f16* __restrict__ b1, f16* __restrict__ b2,
                                f16* __restrict__ b3) {
  const int total4 = (8388608 + 4 * 4194304) / 4;
  for (int i = blockIdx.x * blockDim.x + threadIdx.x; i < total4;
       i += gridDim.x * blockDim.x) {
    int e = i << 2;
    const float* s; f16* d; int off;
    if (e < 8388608)        { s = x;  d = xb; off = e; }
    else if (e < 12582912)  { s = w0; d = b0; off = e - 8388608; }
    else if (e < 16777216)  { s = w1; d = b1; off = e - 12582912; }
    else if (e < 20971520)  { s = w2; d = b2; off = e - 16777216; }
    else                    { s = w3; d = b3; off = e - 20971520; }
    float4 v = *(const float4*)(s + off);
    f16x4 hv = {(f16)v.x, (f16)v.y, (f16)v.z, (f16)v.w};
    *(f16x4*)(d + off) = hv;
  }
}

// ---------------- 2a) la[nm][m][r] = x @ A_nm  (fp32, q/k/v) ----------------
__global__ __launch_bounds__(256) void lora_x_kernel(
    const float* __restrict__ x, const float* __restrict__ Aq,
    const float* __restrict__ Ak, const float* __restrict__ Av,
    float* __restrict__ la) {
  const int wave = threadIdx.x >> 6, lane = threadIdx.x & 63;
  const int m = blockIdx.x * 4 + wave;
  const float* xrow = x + (size_t)m * 2048;
  const float* As[3] = {Aq, Ak, Av};
  float acc[3][8] = {};
  for (int i = 0; i < 32; ++i) {
    int k = i * 64 + lane;
    float xv = xrow[k];
#pragma unroll
    for (int nm = 0; nm < 3; ++nm) {
      const float4* ap = (const float4*)(As[nm] + (size_t)k * 8);
      float4 a0 = ap[0], a1 = ap[1];
      acc[nm][0] += xv * a0.x; acc[nm][1] += xv * a0.y;
      acc[nm][2] += xv * a0.z; acc[nm][3] += xv * a0.w;
      acc[nm][4] += xv * a1.x; acc[nm][5] += xv * a1.y;
      acc[nm][6] += xv * a1.z; acc[nm][7] += xv * a1.w;
    }
  }
#pragma unroll
  for (int nm = 0; nm < 3; ++nm)
#pragma unroll
    for (int r = 0; r < 8; ++r) {
      float v = acc[nm][r];
#pragma unroll
      for (int off = 1; off < 64; off <<= 1) v += __shfl_xor(v, off);
      acc[nm][r] = v;
    }
  if (lane == 0) {
#pragma unroll
    for (int nm = 0; nm < 3; ++nm)
#pragma unroll
      for (int r = 0; r < 8; ++r)
        la[nm * 32768 + (size_t)m * 8 + r] = acc[nm][r];
  }
}

// ---------------- 2b) lap[m][r] = y @ p_A  (y = f16 attention output) -------
__global__ __launch_bounds__(256) void lora_p_kernel(
    const f16* __restrict__ y, const float* __restrict__ Ap,
    float* __restrict__ lap) {
  const int wave = threadIdx.x >> 6, lane = threadIdx.x & 63;
  const int m = blockIdx.x * 4 + wave;
  const f16* yrow = y + (size_t)m * 2048;
  float acc[8] = {};
  for (int i = 0; i < 4; ++i) {
    int k0 = i * 512 + lane * 8;
    f16x8 yv = *(const f16x8*)(yrow + k0);
#pragma unroll
    for (int j = 0; j < 8; ++j) {
      float xv = (float)yv[j];
      const float4* ap = (const float4*)(Ap + (size_t)(k0 + j) * 8);
      float4 a0 = ap[0], a1 = ap[1];
      acc[0] += xv * a0.x; acc[1] += xv * a0.y;
      acc[2] += xv * a0.z; acc[3] += xv * a0.w;
      acc[4] += xv * a1.x; acc[5] += xv * a1.y;
      acc[6] += xv * a1.z; acc[7] += xv * a1.w;
    }
  }
#pragma unroll
  for (int r = 0; r < 8; ++r) {
    float v = acc[r];
#pragma unroll
    for (int off = 1; off < 64; off <<= 1) v += __shfl_xor(v, off);
    acc[r] = v;
  }
  if (lane == 0) {
#pragma unroll
    for (int r = 0; r < 8; ++r) lap[(size_t)m * 8 + r] = acc[r];
  }
}

// ---------------- 3/6) MFMA GEMM: C = A(f16) @ W^T + b + la@Bm ----------------
// MODE 0: rope epilogue -> f16 [B,H,T,D]   (q,k; N-tile==one head)
// MODE 1: plain f16 [B,T,C]                (v)
// MODE 2: fp32 [B,T,C]                     (p -> d_out)
template <int MODE>
__global__ __launch_bounds__(256, 2) void gemm_kernel(
    const f16* __restrict__ A, const f16* __restrict__ Bw,
    const float* __restrict__ bias, const float* __restrict__ la,
    const float* __restrict__ Bm, const int* __restrict__ use_lora,
    const float* __restrict__ cosT, const float* __restrict__ sinT,
    void* __restrict__ out) {
  __shared__ char smem[32768];
  const int tid = threadIdx.x;
  const int wave = tid >> 6, lane = tid & 63;
  const int lr = lane & 15, lg = lane >> 4;
  const int bm = blockIdx.x >> 4, bn = blockIdx.x & 15;
  const int m0 = bm << 7, n0 = bn << 7;
  const int wr = wave >> 1, wc = wave & 1;

  // staging: LDS linear dest, pre-swizzled global source (XOR (row&7)<<4)
  uint aoff[4], boff[4];
#pragma unroll
  for (int r = 0; r < 4; ++r) {
    uint beta = (uint)(wave * 4 + r) * 1024 + (uint)lane * 16;
    uint row = beta >> 7;
    uint c = (beta & 127u) ^ ((row & 7u) << 4);
    aoff[r] = (uint)(m0 + row) * 4096 + c;
    boff[r] = (uint)(n0 + row) * 4096 + c;
  }
  const char* Ab = (const char*)A;
  const char* Bb = (const char*)Bw;

  f32x4 acc[4][4] = {};

  for (int kt = 0; kt < 32; ++kt) {
    __syncthreads();
    const int kb = kt << 7;
#pragma unroll
    for (int r = 0; r < 4; ++r) {
      gl_lds16(Ab + (size_t)(aoff[r] + kb), smem + (wave * 4 + r) * 1024);
      gl_lds16(Bb + (size_t)(boff[r] + kb), smem + 16384 + (wave * 4 + r) * 1024);
    }
    __syncthreads();

    f16x8 af[2][4], bf[2][4];
#pragma unroll
    for (int ks = 0; ks < 2; ++ks) {
#pragma unroll
      for (int mi = 0; mi < 4; ++mi) {
        int row = wr * 64 + mi * 16 + lr;
        int c = (ks * 64 + lg * 16) ^ ((row & 7) << 4);
        af[ks][mi] = *(const f16x8*)(smem + row * 128 + c);
      }
#pragma unroll
      for (int ni = 0; ni < 4; ++ni) {
        int row = wc * 64 + ni * 16 + lr;
        int c = (ks * 64 + lg * 16) ^ ((row & 7) << 4);
        bf[ks][ni] = *(const f16x8*)(smem + 16384 + row * 128 + c);
      }
    }
    __builtin_amdgcn_s_setprio(1);
#pragma unroll
    for (int ks = 0; ks < 2; ++ks)
#pragma unroll
      for (int mi = 0; mi < 4; ++mi)
#pragma unroll
        for (int ni = 0; ni < 4; ++ni)
          acc[mi][ni] = __builtin_amdgcn_mfma_f32_16x16x32_f16(
              af[ks][mi], bf[ks][ni], acc[mi][ni], 0, 0, 0);
    __builtin_amdgcn_s_setprio(0);
  }

  const int ul = use_lora[0];
  __syncthreads();  // smem reuse for output staging (MODE<2)

  float bv[4], bml[4][8];
#pragma unroll
  for (int ni = 0; ni < 4; ++ni) {
    int n = n0 + wc * 64 + ni * 16 + lr;
    bv[ni] = bias[n];
    if (ul) {
#pragma unroll
      for (int r = 0; r < 8; ++r) bml[ni][r] = Bm[r * 2048 + n];
    }
  }

  f16* stg = (f16*)smem;
#pragma unroll
  for (int mi = 0; mi < 4; ++mi) {
    const int mbase = m0 + wr * 64 + mi * 16 + lg * 4;
    float lar[4][8];
    if (ul) {
#pragma unroll
      for (int rg = 0; rg < 4; ++rg) {
        const float4* lp = (const float4*)(la + (size_t)(mbase + rg) * 8);
        float4 l0 = lp[0], l1 = lp[1];
        lar[rg][0] = l0.x; lar[rg][1] = l0.y; lar[rg][2] = l0.z; lar[rg][3] = l0.w;
        lar[rg][4] = l1.x; lar[rg][5] = l1.y; lar[rg][6] = l1.z; lar[rg][7] = l1.w;
      }
    }
#pragma unroll
    for (int ni = 0; ni < 4; ++ni) {
      const int n = n0 + wc * 64 + ni * 16 + lr;
#pragma unroll
      for (int rg = 0; rg < 4; ++rg) {
        float v = acc[mi][ni][rg] + bv[ni];
        if (ul) {
#pragma unroll
          for (int r = 0; r < 8; ++r) v += lar[rg][r] * bml[ni][r];
        }
        if (MODE == 0) {
          float pv = __shfl_xor(v, 1);  // partner column (RoPE pair)
          const int m = mbase + rg;
          const int t = m & 2047;
          const int d = n & 127;
          const int ci = t * 64 + (d >> 1);
          float cs = cosT[ci], sn = sinT[ci];
          float res = ((lane & 1) == 0) ? (v * cs - pv * sn)
                                        : (pv * sn + v * cs);
          stg[(wr * 64 + mi * 16 + lg * 4 + rg) * 128 +
              (wc * 64 + ni * 16 + lr)] = (f16)res;
        } else if (MODE == 1) {
          stg[(wr * 64 + mi * 16 + lg * 4 + rg) * 128 +
              (wc * 64 + ni * 16 + lr)] = (f16)v;
        } else {
          ((float*)out)[(size_t)(mbase + rg) * 2048 + n] = v;
        }
      }
    }
  }

  if (MODE < 2) {
    __syncthreads();
    if (MODE == 0) {
      // tile cols n0..n0+127 == head bn fully; rows -> (b,t)
      const long b_ = m0 >> 11;
      const int tb = m0 & 2047;
      char* obase = (char*)out + ((b_ * 16 + bn) * 2048 + tb) * 256;
#pragma unroll
      for (int p = 0; p < 8; ++p) {
        int s = p * 4096 + tid * 16;
        int row = s >> 8, c = s & 255;
        *(uint4*)(obase + (long)row * 256 + c) = *(const uint4*)(smem + s);
      }
    } else {
      char* obase = (char*)out + ((long)m0 * 2048 + n0) * 2;
#pragma unroll
      for (int p = 0; p < 8; ++p) {
        int s = p * 4096 + tid * 16;
        int row = s >> 8, c = s & 255;
        *(uint4*)(obase + (long)row * 4096 + c) = *(const uint4*)(smem + s);
      }
    }
  }
}

// ---------------- 4) v [B,T,H,D] -> vt [B,H,D,T] ----------------
__global__ void transpose_v_kernel(const ushort* __restrict__ vbi,
                                   ushort* __restrict__ vto) {
  __shared__ ushort tile[32][33];
  const int t0 = blockIdx.x << 5;
  const int d0 = blockIdx.y << 5;
  const int bh = blockIdx.z;
  const int b = bh >> 4, h = bh & 15;
  const int tx = threadIdx.x, ty = threadIdx.y;
  const ushort* src = vbi + ((size_t)(b * 2048 + t0)) * 2048 + h * 128 + d0;
#pragma unroll
  for (int i = 0; i < 4; ++i)
    tile[ty + 8 * i][tx] = src[(size_t)(ty + 8 * i) * 2048 + tx];
  __syncthreads();
  ushort* dst = vto + ((size_t)bh * 128 + d0) * 2048 + t0;
#pragma unroll
  for (int i = 0; i < 4; ++i)
    dst[(size_t)(ty + 8 * i) * 2048 + tx] = tile[tx][ty + 8 * i];
}

// ---------------- 5) causal flash attention (swapped-operand, in-reg softmax)
// 4 waves, 64 q-rows per block, KV tiles of 64. q-tiles reversed (long first).
// S^T = mfma(K,Q): lane holds S[k=kv0+n*16+lg*4+rg][q=lr]  (16 vals, 1 q-row)
// O^T = mfma(V,P): lane holds O[q=lr][d=dt*16+lg*4+rg]
__global__ __launch_bounds__(256, 2) void attn_kernel(
    const f16* __restrict__ qr, const f16* __restrict__ kr,
    const f16* __restrict__ vt, f16* __restrict__ y) {
  __shared__ char smem[32768];
  char* Ks = smem;            // 64 x 256B (xor-swizzled)
  char* Vs = smem + 16384;    // 128 x 128B (xor-swizzled)
  const int tid = threadIdx.x, wave = tid >> 6, lane = tid & 63;
  const int lr = lane & 15, lg = lane >> 4;
  const int qtile = 31 - (int)blockIdx.x;  // longest blocks dispatch first
  const int q0 = qtile << 6;
  const int h = blockIdx.y, b = blockIdx.z;
  const long bh = b * 16 + h;

  const char* qbase = (const char*)qr + (bh * 2048 + q0 + wave * 16 + lr) * 256;
  f16x8 qf[4];
#pragma unroll
  for (int ks = 0; ks < 4; ++ks)
    qf[ks] = *(const f16x8*)(qbase + ks * 64 + lg * 16);

  f32x4 o[8] = {};
  float mrow = -3e38f, lsum = 0.f;  // per-lane state for q-row (lr)
  const int qa = q0 + wave * 16 + lr;

  const char* kbase = (const char*)kr + bh * 2048 * 256;
  const char* vbase = (const char*)vt + bh * 128 * 4096;
  const float SC2 = 0.12752551286084103f;  // (1/sqrt(128))*log2(e)

  for (int kt = 0; kt <= qtile; ++kt) {
    const int kv0 = kt << 6;
    __syncthreads();
#pragma unroll
    for (int r = 0; r < 4; ++r) {
      uint s = (uint)(wave * 4 + r) * 1024 + (uint)lane * 16;
      {
        uint row = s >> 8, c = (s & 255u) ^ ((row & 7u) << 4);
        gl_lds16(kbase + (size_t)(kv0 + row) * 256 + c,
                 Ks + (wave * 4 + r) * 1024);
      }
      {
        uint row = s >> 7, c = (s & 127u) ^ ((row & 7u) << 4);
        gl_lds16(vbase + (size_t)row * 4096 + kv0 * 2 + c,
                 Vs + (wave * 4 + r) * 1024);
      }
    }
    __syncthreads();

    // QK^T swapped: sa[n][rg] = S[k][q=lr]
    f32x4 sa[4] = {};
    __builtin_amdgcn_s_setprio(1);
#pragma unroll
    for (int ks = 0; ks < 4; ++ks)
#pragma unroll
      for (int n = 0; n < 4; ++n) {
        int row = n * 16 + lr;
        int c = (ks * 64 + lg * 16) ^ ((row & 7) << 4);
        f16x8 kf = *(const f16x8*)(Ks + row * 256 + c);
        sa[n] = __builtin_amdgcn_mfma_f32_16x16x32_f16(kf, qf[ks], sa[n], 0, 0, 0);
      }
    __builtin_amdgcn_s_setprio(0);

    // in-register softmax over the lane's 16 S values
    float L[16];
    float pm = -3e38f;
    const bool diag = (kt == qtile);
#pragma unroll
    for (int n = 0; n < 4; ++n)
#pragma unroll
      for (int rg = 0; rg < 4; ++rg) {
        float Lv = sa[n][rg] * SC2;
        if (diag && (kv0 + n * 16 + lg * 4 + rg > qa)) Lv = -3e37f;
        L[n * 4 + rg] = Lv;
        pm = fmaxf(pm, Lv);
      }
    pm = fmaxf(pm, __shfl_xor(pm, 16));
    pm = fmaxf(pm, __shfl_xor(pm, 32));
    float mn = fmaxf(mrow, pm);
    float alpha = exp2f(mrow - mn);
    mrow = mn;
    float ps = 0.f;
#pragma unroll
    for (int i = 0; i < 16; ++i) {
      float p = exp2f(L[i] - mn);
      L[i] = p;
      ps += p;
    }
    ps += __shfl_xor(ps, 16);
    ps += __shfl_xor(ps, 32);
    lsum = lsum * alpha + ps;
#pragma unroll
    for (int dt = 0; dt < 8; ++dt)
#pragma unroll
      for (int rg = 0; rg < 4; ++rg) o[dt][rg] *= alpha;

    // P -> B-fragment via in-register 4-lane word transpose
#pragma unroll
    for (int ks2 = 0; ks2 < 2; ++ks2) {
      uint w0 = pkrtz(L[8 * ks2 + 0], L[8 * ks2 + 1]);
      uint w1 = pkrtz(L[8 * ks2 + 2], L[8 * ks2 + 3]);
      uint w2 = pkrtz(L[8 * ks2 + 4], L[8 * ks2 + 5]);
      uint w3 = pkrtz(L[8 * ks2 + 6], L[8 * ks2 + 7]);
      int src1 = ((lg & 1) << 5) + lr;  // lane of lg' = 2*(lg&1)
      int src2 = src1 + 16;             // lane of lg' = 2*(lg&1)+1
      uint a0 = __shfl((int)w0, src1), a1 = __shfl((int)w1, src1);
      uint a2 = __shfl((int)w2, src1), a3 = __shfl((int)w3, src1);
      uint b0 = __shfl((int)w0, src2), b1 = __shfl((int)w1, src2);
      uint b2 = __shfl((int)w2, src2), b3 = __shfl((int)w3, src2);
      const bool hi = (lg >> 1) != 0;
      uint4 uu;
      uu.x = hi ? a2 : a0;
      uu.y = hi ? a3 : a1;
      uu.z = hi ? b2 : b0;
      uu.w = hi ? b3 : b1;
      f16x8 pf = __builtin_bit_cast(f16x8, uu);
      __builtin_amdgcn_s_setprio(1);
#pragma unroll
      for (int dt = 0; dt < 8; ++dt) {
        int drow = dt * 16 + lr;
        int c = (ks2 * 64 + lg * 16) ^ ((drow & 7) << 4);
        f16x8 vf = *(const f16x8*)(Vs + drow * 128 + c);
        o[dt] = __builtin_amdgcn_mfma_f32_16x16x32_f16(vf, pf, o[dt], 0, 0, 0);
      }
      __builtin_amdgcn_s_setprio(0);
    }
  }

  // epilogue: normalize, stage in LDS (swizzled), coalesced store to y [B,T,C]
  __syncthreads();
  const float inv = 1.f / lsum;
  {
    const int row = wave * 16 + lr;
#pragma unroll
    for (int dt = 0; dt < 8; ++dt) {
      uint lo = pkrtz(o[dt][0] * inv, o[dt][1] * inv);
      uint hi2 = pkrtz(o[dt][2] * inv, o[dt][3] * inv);
      int c = (dt * 32 + lg * 8) ^ ((row & 7) << 4);
      uint2 w; w.x = lo; w.y = hi2;
      *(uint2*)(smem + row * 256 + c) = w;
    }
  }
  __syncthreads();
#pragma unroll
  for (int p = 0; p < 4; ++p) {
    int s = p * 4096 + tid * 16;
    int row = s >> 8, cb = s & 255;
    int c = cb ^ ((row & 7) << 4);
    char* dst = (char*)y + ((long)(b * 2048 + q0 + row) * 2048 + h * 128) * 2 + cb;
    *(uint4*)dst = *(const uint4*)(smem + row * 256 + c);
  }
}

// ---------------- launch ----------------
extern "C" void kernel_launch(void* const* d_in, const int* in_sizes, int n_in,
                              void* d_out, int out_size, void* d_ws,
                              size_t ws_size, hipStream_t stream) {
  (void)in_sizes; (void)n_in; (void)out_size; (void)ws_size;
  const float* x   = (const float*)d_in[0];
  const float* q_w = (const float*)d_in[1];
  const float* q_b = (const float*)d_in[2];
  const float* q_A = (const float*)d_in[3];
  const float* q_B = (const float*)d_in[4];
  const float* k_w = (const float*)d_in[5];
  const float* k_b = (const float*)d_in[6];
  const float* k_A = (const float*)d_in[7];
  const float* k_B = (const float*)d_in[8];
  const float* v_w = (const float*)d_in[9];
  const float* v_b = (const float*)d_in[10];
  const float* v_A = (const float*)d_in[11];
  const float* v_B = (const float*)d_in[12];
  const float* p_w = (const float*)d_in[13];
  const float* p_b = (const float*)d_in[14];
  const float* p_A = (const float*)d_in[15];
  const float* p_B = (const float*)d_in[16];
  const float* cosT = (const float*)d_in[17];
  const float* sinT = (const float*)d_in[18];
  const int* use_lora = (const int*)d_in[20];  // mask (19) implicit: causal

  char* ws = (char*)d_ws;
  f16* xb  = (f16*)(ws);                    // 16.78 MB ; later reused as vt
  f16* wqb = (f16*)(ws + 16777216);
  f16* wkb = (f16*)(ws + 25165824);
  f16* wvb = (f16*)(ws + 33554432);
  f16* wpb = (f16*)(ws + 41943040);
  float* la = (float*)(ws + 50331648);      // [4][4096][8] fp32
  f16* qr  = (f16*)(ws + 50855936);         // [B,H,T,D]
  f16* kr  = (f16*)(ws + 67633152);         // [B,H,T,D]
  f16* vb  = (f16*)(ws + 84410368);         // [B,T,C] ; later reused as y
  f16* vt  = (f16*)(ws);                    // [B,H,D,T] aliases xb (xb dead)
  f16* y   = vb;                            // aliases vb (vb dead after transpose)
  float* lap = la + 98304;                  // p-slot, filled from y post-attn

  cast_f16_kernel<<<dim3(2048), dim3(256), 0, stream>>>(
      x, q_w, k_w, v_w, p_w, xb, wqb, wkb, wvb, wpb);
  lora_x_kernel<<<dim3(1024), dim3(256), 0, stream>>>(x, q_A, k_A, v_A, la);
  gemm_kernel<0><<<dim3(512), dim3(256), 0, stream>>>(
      xb, wqb, q_b, la, q_B, use_lora, cosT, sinT, (void*)qr);
  gemm_kernel<0><<<dim3(512), dim3(256), 0, stream>>>(
      xb, wkb, k_b, la + 32768, k_B, use_lora, cosT, sinT, (void*)kr);
  gemm_kernel<1><<<dim3(512), dim3(256), 0, stream>>>(
      xb, wvb, v_b, la + 65536, v_B, use_lora, nullptr, nullptr, (void*)vb);
  transpose_v_kernel<<<dim3(64, 4, 32), dim3(32, 8), 0, stream>>>(
      (const ushort*)vb, (ushort*)vt);
  attn_kernel<<<dim3(32, 16, 2), dim3(256), 0, stream>>>(qr, kr, vt, y);
  lora_p_kernel<<<dim3(1024), dim3(256), 0, stream>>>(y, p_A, lap);
  gemm_kernel<2><<<dim3(512), dim3(256), 0, stream>>>(
      y, wpb, p_b, lap, p_B, use_lora, nullptr, nullptr, d_out);
}

// Round 5
// 393.395 us; speedup vs baseline: 1.1332x; 1.0143x over previous
//
#include <hip/hip_runtime.h>

typedef _Float16 f16;
typedef _Float16 f16x4 __attribute__((ext_vector_type(4)));
typedef _Float16 f16x8 __attribute__((ext_vector_type(8)));
typedef __fp16 hf2 __attribute__((ext_vector_type(2)));
typedef float f32x4 __attribute__((ext_vector_type(4)));

#define DEV static __device__ __forceinline__

DEV void gl_lds16(const void* g, void* l) {
  __builtin_amdgcn_global_load_lds(
      (const __attribute__((address_space(1))) void*)g,
      (__attribute__((address_space(3))) void*)l, 16, 0, 0);
}

DEV uint pkrtz(float a, float b) {
  hf2 h = __builtin_amdgcn_cvt_pkrtz(a, b);
  return __builtin_bit_cast(uint, h);
}

// ---------------- 1) cast fp32 -> fp16 (x + 4 weights) ----------------
__global__ void cast_f16_kernel(const float* __restrict__ x,
                                const float* __restrict__ w0,
                                const float* __restrict__ w1,
                                const float* __restrict__ w2,
                                const float* __restrict__ w3,
                                f16* __restrict__ xb, f16* __restrict__ b0,
                                f16* __restrict__ b1, f16* __restrict__ b2,
                                f16* __restrict__ b3) {
  const int total4 = (8388608 + 4 * 4194304) / 4;
  for (int i = blockIdx.x * blockDim.x + threadIdx.x; i < total4;
       i += gridDim.x * blockDim.x) {
    int e = i << 2;
    const float* s; f16* d; int off;
    if (e < 8388608)        { s = x;  d = xb; off = e; }
    else if (e < 12582912)  { s = w0; d = b0; off = e - 8388608; }
    else if (e < 16777216)  { s = w1; d = b1; off = e - 12582912; }
    else if (e < 20971520)  { s = w2; d = b2; off = e - 16777216; }
    else                    { s = w3; d = b3; off = e - 20971520; }
    float4 v = *(const float4*)(s + off);
    f16x4 hv = {(f16)v.x, (f16)v.y, (f16)v.z, (f16)v.w};
    *(f16x4*)(d + off) = hv;
  }
}

// ---------------- 2a) la[nm][m][r] = x @ A_nm  (fp32, q/k/v) ----------------
__global__ __launch_bounds__(256) void lora_x_kernel(
    const float* __restrict__ x, const float* __restrict__ Aq,
    const float* __restrict__ Ak, const float* __restrict__ Av,
    float* __restrict__ la) {
  const int wave = threadIdx.x >> 6, lane = threadIdx.x & 63;
  const int m = blockIdx.x * 4 + wave;
  const float* xrow = x + (size_t)m * 2048;
  const float* As[3] = {Aq, Ak, Av};
  float acc[3][8] = {};
  for (int i = 0; i < 32; ++i) {
    int k = i * 64 + lane;
    float xv = xrow[k];
#pragma unroll
    for (int nm = 0; nm < 3; ++nm) {
      const float4* ap = (const float4*)(As[nm] + (size_t)k * 8);
      float4 a0 = ap[0], a1 = ap[1];
      acc[nm][0] += xv * a0.x; acc[nm][1] += xv * a0.y;
      acc[nm][2] += xv * a0.z; acc[nm][3] += xv * a0.w;
      acc[nm][4] += xv * a1.x; acc[nm][5] += xv * a1.y;
      acc[nm][6] += xv * a1.z; acc[nm][7] += xv * a1.w;
    }
  }
#pragma unroll
  for (int nm = 0; nm < 3; ++nm)
#pragma unroll
    for (int r = 0; r < 8; ++r) {
      float v = acc[nm][r];
#pragma unroll
      for (int off = 1; off < 64; off <<= 1) v += __shfl_xor(v, off);
      acc[nm][r] = v;
    }
  if (lane == 0) {
#pragma unroll
    for (int nm = 0; nm < 3; ++nm)
#pragma unroll
      for (int r = 0; r < 8; ++r)
        la[nm * 32768 + (size_t)m * 8 + r] = acc[nm][r];
  }
}

// ---------------- 2b) lap[m][r] = y @ p_A  (y = f16 attention output) -------
__global__ __launch_bounds__(256) void lora_p_kernel(
    const f16* __restrict__ y, const float* __restrict__ Ap,
    float* __restrict__ lap) {
  const int wave = threadIdx.x >> 6, lane = threadIdx.x & 63;
  const int m = blockIdx.x * 4 + wave;
  const f16* yrow = y + (size_t)m * 2048;
  float acc[8] = {};
  for (int i = 0; i < 4; ++i) {
    int k0 = i * 512 + lane * 8;
    f16x8 yv = *(const f16x8*)(yrow + k0);
#pragma unroll
    for (int j = 0; j < 8; ++j) {
      float xv = (float)yv[j];
      const float4* ap = (const float4*)(Ap + (size_t)(k0 + j) * 8);
      float4 a0 = ap[0], a1 = ap[1];
      acc[0] += xv * a0.x; acc[1] += xv * a0.y;
      acc[2] += xv * a0.z; acc[3] += xv * a0.w;
      acc[4] += xv * a1.x; acc[5] += xv * a1.y;
      acc[6] += xv * a1.z; acc[7] += xv * a1.w;
    }
  }
#pragma unroll
  for (int r = 0; r < 8; ++r) {
    float v = acc[r];
#pragma unroll
    for (int off = 1; off < 64; off <<= 1) v += __shfl_xor(v, off);
    acc[r] = v;
  }
  if (lane == 0) {
#pragma unroll
    for (int r = 0; r < 8; ++r) lap[(size_t)m * 8 + r] = acc[r];
  }
}

// ---------------- 3/6) MFMA GEMM: C = A(f16) @ W^T + b + la@Bm ----------------
// MODE 0: rope epilogue -> f16 [B,H,T,D]   (q,k; N-tile==one head)
// MODE 1: plain f16 [B,T,C]                (v)
// MODE 2: fp32 [B,T,C]                     (p -> d_out)
template <int MODE>
__global__ __launch_bounds__(256, 2) void gemm_kernel(
    const f16* __restrict__ A, const f16* __restrict__ Bw,
    const float* __restrict__ bias, const float* __restrict__ la,
    const float* __restrict__ Bm, const int* __restrict__ use_lora,
    const float* __restrict__ cosT, const float* __restrict__ sinT,
    void* __restrict__ out) {
  __shared__ char smem[32768];
  const int tid = threadIdx.x;
  const int wave = tid >> 6, lane = tid & 63;
  const int lr = lane & 15, lg = lane >> 4;
  const int bm = blockIdx.x >> 4, bn = blockIdx.x & 15;
  const int m0 = bm << 7, n0 = bn << 7;
  const int wr = wave >> 1, wc = wave & 1;

  // staging: LDS linear dest, pre-swizzled global source (XOR (row&7)<<4)
  uint aoff[4], boff[4];
#pragma unroll
  for (int r = 0; r < 4; ++r) {
    uint beta = (uint)(wave * 4 + r) * 1024 + (uint)lane * 16;
    uint row = beta >> 7;
    uint c = (beta & 127u) ^ ((row & 7u) << 4);
    aoff[r] = (uint)(m0 + row) * 4096 + c;
    boff[r] = (uint)(n0 + row) * 4096 + c;
  }
  const char* Ab = (const char*)A;
  const char* Bb = (const char*)Bw;

  f32x4 acc[4][4] = {};

  for (int kt = 0; kt < 32; ++kt) {
    __syncthreads();
    const int kb = kt << 7;
#pragma unroll
    for (int r = 0; r < 4; ++r) {
      gl_lds16(Ab + (size_t)(aoff[r] + kb), smem + (wave * 4 + r) * 1024);
      gl_lds16(Bb + (size_t)(boff[r] + kb), smem + 16384 + (wave * 4 + r) * 1024);
    }
    __syncthreads();

    f16x8 af[2][4], bf[2][4];
#pragma unroll
    for (int ks = 0; ks < 2; ++ks) {
#pragma unroll
      for (int mi = 0; mi < 4; ++mi) {
        int row = wr * 64 + mi * 16 + lr;
        int c = (ks * 64 + lg * 16) ^ ((row & 7) << 4);
        af[ks][mi] = *(const f16x8*)(smem + row * 128 + c);
      }
#pragma unroll
      for (int ni = 0; ni < 4; ++ni) {
        int row = wc * 64 + ni * 16 + lr;
        int c = (ks * 64 + lg * 16) ^ ((row & 7) << 4);
        bf[ks][ni] = *(const f16x8*)(smem + 16384 + row * 128 + c);
      }
    }
    __builtin_amdgcn_s_setprio(1);
#pragma unroll
    for (int ks = 0; ks < 2; ++ks)
#pragma unroll
      for (int mi = 0; mi < 4; ++mi)
#pragma unroll
        for (int ni = 0; ni < 4; ++ni)
          acc[mi][ni] = __builtin_amdgcn_mfma_f32_16x16x32_f16(
              af[ks][mi], bf[ks][ni], acc[mi][ni], 0, 0, 0);
    __builtin_amdgcn_s_setprio(0);
  }

  const int ul = use_lora[0];
  __syncthreads();  // smem reuse for output staging (MODE<2)

  float bv[4], bml[4][8];
#pragma unroll
  for (int ni = 0; ni < 4; ++ni) {
    int n = n0 + wc * 64 + ni * 16 + lr;
    bv[ni] = bias[n];
    if (ul) {
#pragma unroll
      for (int r = 0; r < 8; ++r) bml[ni][r] = Bm[r * 2048 + n];
    }
  }

  f16* stg = (f16*)smem;
#pragma unroll
  for (int mi = 0; mi < 4; ++mi) {
    const int mbase = m0 + wr * 64 + mi * 16 + lg * 4;
    float lar[4][8];
    if (ul) {
#pragma unroll
      for (int rg = 0; rg < 4; ++rg) {
        const float4* lp = (const float4*)(la + (size_t)(mbase + rg) * 8);
        float4 l0 = lp[0], l1 = lp[1];
        lar[rg][0] = l0.x; lar[rg][1] = l0.y; lar[rg][2] = l0.z; lar[rg][3] = l0.w;
        lar[rg][4] = l1.x; lar[rg][5] = l1.y; lar[rg][6] = l1.z; lar[rg][7] = l1.w;
      }
    }
#pragma unroll
    for (int ni = 0; ni < 4; ++ni) {
      const int n = n0 + wc * 64 + ni * 16 + lr;
#pragma unroll
      for (int rg = 0; rg < 4; ++rg) {
        float v = acc[mi][ni][rg] + bv[ni];
        if (ul) {
#pragma unroll
          for (int r = 0; r < 8; ++r) v += lar[rg][r] * bml[ni][r];
        }
        if (MODE == 0) {
          float pv = __shfl_xor(v, 1);  // partner column (RoPE pair)
          const int m = mbase + rg;
          const int t = m & 2047;
          const int d = n & 127;
          const int ci = t * 64 + (d >> 1);
          float cs = cosT[ci], sn = sinT[ci];
          float res = ((lane & 1) == 0) ? (v * cs - pv * sn)
                                        : (pv * sn + v * cs);
          stg[(wr * 64 + mi * 16 + lg * 4 + rg) * 128 +
              (wc * 64 + ni * 16 + lr)] = (f16)res;
        } else if (MODE == 1) {
          stg[(wr * 64 + mi * 16 + lg * 4 + rg) * 128 +
              (wc * 64 + ni * 16 + lr)] = (f16)v;
        } else {
          ((float*)out)[(size_t)(mbase + rg) * 2048 + n] = v;
        }
      }
    }
  }

  if (MODE < 2) {
    __syncthreads();
    if (MODE == 0) {
      // tile cols n0..n0+127 == head bn fully; rows -> (b,t)
      const long b_ = m0 >> 11;
      const int tb = m0 & 2047;
      char* obase = (char*)out + ((b_ * 16 + bn) * 2048 + tb) * 256;
#pragma unroll
      for (int p = 0; p < 8; ++p) {
        int s = p * 4096 + tid * 16;
        int row = s >> 8, c = s & 255;
        *(uint4*)(obase + (long)row * 256 + c) = *(const uint4*)(smem + s);
      }
    } else {
      char* obase = (char*)out + ((long)m0 * 2048 + n0) * 2;
#pragma unroll
      for (int p = 0; p < 8; ++p) {
        int s = p * 4096 + tid * 16;
        int row = s >> 8, c = s & 255;
        *(uint4*)(obase + (long)row * 4096 + c) = *(const uint4*)(smem + s);
      }
    }
  }
}

// ---------------- 4) v [B,T,H,D] -> vt [B,H,D,T] ----------------
__global__ void transpose_v_kernel(const ushort* __restrict__ vbi,
                                   ushort* __restrict__ vto) {
  __shared__ ushort tile[32][33];
  const int t0 = blockIdx.x << 5;
  const int d0 = blockIdx.y << 5;
  const int bh = blockIdx.z;
  const int b = bh >> 4, h = bh & 15;
  const int tx = threadIdx.x, ty = threadIdx.y;
  const ushort* src = vbi + ((size_t)(b * 2048 + t0)) * 2048 + h * 128 + d0;
#pragma unroll
  for (int i = 0; i < 4; ++i)
    tile[ty + 8 * i][tx] = src[(size_t)(ty + 8 * i) * 2048 + tx];
  __syncthreads();
  ushort* dst = vto + ((size_t)bh * 128 + d0) * 2048 + t0;
#pragma unroll
  for (int i = 0; i < 4; ++i)
    dst[(size_t)(ty + 8 * i) * 2048 + tx] = tile[tx][ty + 8 * i];
}

// ---------------- 5) causal flash attention v2 ----------------
// 4 waves; 128 q-rows/block (per wave: 2 groups of 16, rows wave*32+g*16+lr);
// KV tiles of 64, double-buffered (2 x 32KB), ONE barrier per tile.
// Each K/V fragment read feeds both q-groups (2 MFMA per ds_read_b128).
// S^T = mfma(K,Q): lane holds S[k=kv0+n*16+lg*4+rg][q=lr]
// O^T = mfma(V,P): lane holds O[q=lr][d=dt*16+lg*4+rg]
__global__ __launch_bounds__(256, 2) void attn_kernel(
    const f16* __restrict__ qr, const f16* __restrict__ kr,
    const f16* __restrict__ vt, f16* __restrict__ y) {
  extern __shared__ char smem[];  // 2 x (K 16KB + V 16KB) = 64KB
  const int tid = threadIdx.x, wave = tid >> 6, lane = tid & 63;
  const int lr = lane & 15, lg = lane >> 4;
  const int qt = 15 - (int)blockIdx.x;  // longest blocks dispatch first
  const int q0 = qt << 7;
  const int h = blockIdx.y, b = blockIdx.z;
  const long bh = b * 16 + h;
  const int nt = 2 * qt + 2;  // KV tiles of 64 covering 0..q0+127

  const char* kbase = (const char*)kr + bh * 2048 * 256;
  const char* vbase = (const char*)vt + bh * 128 * 4096;

  f16x8 qf[2][4];
#pragma unroll
  for (int g = 0; g < 2; ++g) {
    const char* qb =
        (const char*)qr + (bh * 2048 + q0 + wave * 32 + g * 16 + lr) * 256;
#pragma unroll
    for (int ks = 0; ks < 4; ++ks)
      qf[g][ks] = *(const f16x8*)(qb + ks * 64 + lg * 16);
  }

  f32x4 o[2][8] = {};
  float mrow[2] = {-3e38f, -3e38f};
  float lsum[2] = {0.f, 0.f};
  const float SC2 = 0.12752551286084103f;  // (1/sqrt(128))*log2(e)

  auto STAGE = [&](int kv0, int bsel) {
    char* Ks = smem + bsel * 32768;
    char* Vs = Ks + 16384;
#pragma unroll
    for (int r = 0; r < 4; ++r) {
      uint s = (uint)(wave * 4 + r) * 1024 + (uint)lane * 16;
      uint rowk = s >> 8, ck = (s & 255u) ^ ((rowk & 7u) << 4);
      gl_lds16(kbase + (size_t)(kv0 + rowk) * 256 + ck,
               Ks + (wave * 4 + r) * 1024);
      uint rowv = s >> 7, cv = (s & 127u) ^ ((rowv & 7u) << 4);
      gl_lds16(vbase + (size_t)rowv * 4096 + kv0 * 2 + cv,
               Vs + (wave * 4 + r) * 1024);
    }
  };

  STAGE(0, 0);
  __syncthreads();  // vmcnt drained by barrier

  for (int kt = 0; kt < nt; ++kt) {
    const int kv0 = kt << 6;
    if (kt + 1 < nt) STAGE((kt + 1) << 6, (kt + 1) & 1);
    const char* Ks = smem + (kt & 1) * 32768;
    const char* Vs = Ks + 16384;

    // wave-uniform skip: tile fully masked for BOTH groups (act0<=>act1)
    if (kv0 <= q0 + wave * 32 + 31) {
      f32x4 sa[2][4] = {};
      __builtin_amdgcn_s_setprio(1);
#pragma unroll
      for (int ks = 0; ks < 4; ++ks)
#pragma unroll
        for (int n = 0; n < 4; ++n) {
          int row = n * 16 + lr;
          int c = (ks * 64 + lg * 16) ^ ((row & 7) << 4);
          f16x8 kf = *(const f16x8*)(Ks + row * 256 + c);
          sa[0][n] =
              __builtin_amdgcn_mfma_f32_16x16x32_f16(kf, qf[0][ks], sa[0][n], 0, 0, 0);
          sa[1][n] =
              __builtin_amdgcn_mfma_f32_16x16x32_f16(kf, qf[1][ks], sa[1][n], 0, 0, 0);
        }
      __builtin_amdgcn_s_setprio(0);

      f16x8 pf[2][2];
#pragma unroll
      for (int g = 0; g < 2; ++g) {
        const int qgbase = q0 + wave * 32 + g * 16;
        float L[16];
        float pm = -3e38f;
        const bool dm = (kv0 + 63 > qgbase);
#pragma unroll
        for (int n = 0; n < 4; ++n)
#pragma unroll
          for (int rg = 0; rg < 4; ++rg) {
            float Lv = sa[g][n][rg] * SC2;
            if (dm && (kv0 + n * 16 + lg * 4 + rg > qgbase + lr)) Lv = -3e37f;
            L[n * 4 + rg] = Lv;
            pm = fmaxf(pm, Lv);
          }
        pm = fmaxf(pm, __shfl_xor(pm, 16));
        pm = fmaxf(pm, __shfl_xor(pm, 32));
        float mn = fmaxf(mrow[g], pm);
        float alpha = exp2f(mrow[g] - mn);
        mrow[g] = mn;
        float ps = 0.f;
#pragma unroll
        for (int i = 0; i < 16; ++i) {
          float p = exp2f(L[i] - mn);
          L[i] = p;
          ps += p;
        }
        ps += __shfl_xor(ps, 16);
        ps += __shfl_xor(ps, 32);
        lsum[g] = lsum[g] * alpha + ps;
#pragma unroll
        for (int dt = 0; dt < 8; ++dt)
#pragma unroll
          for (int rg = 0; rg < 4; ++rg) o[g][dt][rg] *= alpha;

        // P -> B-fragment via in-register 4-lane word transpose
#pragma unroll
        for (int ks2 = 0; ks2 < 2; ++ks2) {
          uint w0 = pkrtz(L[8 * ks2 + 0], L[8 * ks2 + 1]);
          uint w1 = pkrtz(L[8 * ks2 + 2], L[8 * ks2 + 3]);
          uint w2 = pkrtz(L[8 * ks2 + 4], L[8 * ks2 + 5]);
          uint w3 = pkrtz(L[8 * ks2 + 6], L[8 * ks2 + 7]);
          int src1 = ((lg & 1) << 5) + lr;
          int src2 = src1 + 16;
          uint a0 = __shfl((int)w0, src1), a1 = __shfl((int)w1, src1);
          uint a2 = __shfl((int)w2, src1), a3 = __shfl((int)w3, src1);
          uint b0 = __shfl((int)w0, src2), b1 = __shfl((int)w1, src2);
          uint b2 = __shfl((int)w2, src2), b3 = __shfl((int)w3, src2);
          const bool hi = (lg >> 1) != 0;
          uint4 uu;
          uu.x = hi ? a2 : a0;
          uu.y = hi ? a3 : a1;
          uu.z = hi ? b2 : b0;
          uu.w = hi ? b3 : b1;
          pf[g][ks2] = __builtin_bit_cast(f16x8, uu);
        }
      }

      // PV: each V fragment feeds both q-groups
#pragma unroll
      for (int ks2 = 0; ks2 < 2; ++ks2) {
        __builtin_amdgcn_s_setprio(1);
#pragma unroll
        for (int dt = 0; dt < 8; ++dt) {
          int drow = dt * 16 + lr;
          int c = (ks2 * 64 + lg * 16) ^ ((drow & 7) << 4);
          f16x8 vf = *(const f16x8*)(Vs + drow * 128 + c);
          o[0][dt] =
              __builtin_amdgcn_mfma_f32_16x16x32_f16(vf, pf[0][ks2], o[0][dt], 0, 0, 0);
          o[1][dt] =
              __builtin_amdgcn_mfma_f32_16x16x32_f16(vf, pf[1][ks2], o[1][dt], 0, 0, 0);
        }
        __builtin_amdgcn_s_setprio(0);
      }
    }
    __syncthreads();  // drains next-tile loads; protects buffer swap
  }

  // epilogue: normalize, stage 128x256B in LDS (swizzled), coalesced store
#pragma unroll
  for (int g = 0; g < 2; ++g) {
    const float inv = 1.f / lsum[g];
    const int row = wave * 32 + g * 16 + lr;
#pragma unroll
    for (int dt = 0; dt < 8; ++dt) {
      uint lo = pkrtz(o[g][dt][0] * inv, o[g][dt][1] * inv);
      uint hi2 = pkrtz(o[g][dt][2] * inv, o[g][dt][3] * inv);
      int c = (dt * 32 + lg * 8) ^ ((row & 7) << 4);
      uint2 w;
      w.x = lo;
      w.y = hi2;
      *(uint2*)(smem + row * 256 + c) = w;
    }
  }
  __syncthreads();
#pragma unroll
  for (int p = 0; p < 8; ++p) {
    int s = p * 4096 + tid * 16;
    int row = s >> 8, cb = s & 255;
    int c = cb ^ ((row & 7) << 4);
    char* dst =
        (char*)y + ((long)(b * 2048 + q0 + row) * 2048 + h * 128) * 2 + cb;
    *(uint4*)dst = *(const uint4*)(smem + row * 256 + c);
  }
}

// ---------------- launch ----------------
extern "C" void kernel_launch(void* const* d_in, const int* in_sizes, int n_in,
                              void* d_out, int out_size, void* d_ws,
                              size_t ws_size, hipStream_t stream) {
  (void)in_sizes; (void)n_in; (void)out_size; (void)ws_size;
  const float* x   = (const float*)d_in[0];
  const float* q_w = (const float*)d_in[1];
  const float* q_b = (const float*)d_in[2];
  const float* q_A = (const float*)d_in[3];
  const float* q_B = (const float*)d_in[4];
  const float* k_w = (const float*)d_in[5];
  const float* k_b = (const float*)d_in[6];
  const float* k_A = (const float*)d_in[7];
  const float* k_B = (const float*)d_in[8];
  const float* v_w = (const float*)d_in[9];
  const float* v_b = (const float*)d_in[10];
  const float* v_A = (const float*)d_in[11];
  const float* v_B = (const float*)d_in[12];
  const float* p_w = (const float*)d_in[13];
  const float* p_b = (const float*)d_in[14];
  const float* p_A = (const float*)d_in[15];
  const float* p_B = (const float*)d_in[16];
  const float* cosT = (const float*)d_in[17];
  const float* sinT = (const float*)d_in[18];
  const int* use_lora = (const int*)d_in[20];  // mask (19) implicit: causal

  char* ws = (char*)d_ws;
  f16* xb  = (f16*)(ws);                    // 16.78 MB ; later reused as vt
  f16* wqb = (f16*)(ws + 16777216);
  f16* wkb = (f16*)(ws + 25165824);
  f16* wvb = (f16*)(ws + 33554432);
  f16* wpb = (f16*)(ws + 41943040);
  float* la = (float*)(ws + 50331648);      // [4][4096][8] fp32
  f16* qr  = (f16*)(ws + 50855936);         // [B,H,T,D]
  f16* kr  = (f16*)(ws + 67633152);         // [B,H,T,D]
  f16* vb  = (f16*)(ws + 84410368);         // [B,T,C] ; later reused as y
  f16* vt  = (f16*)(ws);                    // [B,H,D,T] aliases xb (xb dead)
  f16* y   = vb;                            // aliases vb (vb dead after transpose)
  float* lap = la + 98304;                  // p-slot, filled from y post-attn

  cast_f16_kernel<<<dim3(2048), dim3(256), 0, stream>>>(
      x, q_w, k_w, v_w, p_w, xb, wqb, wkb, wvb, wpb);
  lora_x_kernel<<<dim3(1024), dim3(256), 0, stream>>>(x, q_A, k_A, v_A, la);
  gemm_kernel<0><<<dim3(512), dim3(256), 0, stream>>>(
      xb, wqb, q_b, la, q_B, use_lora, cosT, sinT, (void*)qr);
  gemm_kernel<0><<<dim3(512), dim3(256), 0, stream>>>(
      xb, wkb, k_b, la + 32768, k_B, use_lora, cosT, sinT, (void*)kr);
  gemm_kernel<1><<<dim3(512), dim3(256), 0, stream>>>(
      xb, wvb, v_b, la + 65536, v_B, use_lora, nullptr, nullptr, (void*)vb);
  transpose_v_kernel<<<dim3(64, 4, 32), dim3(32, 8), 0, stream>>>(
      (const ushort*)vb, (ushort*)vt);
  attn_kernel<<<dim3(16, 16, 2), dim3(256), 65536, stream>>>(qr, kr, vt, y);
  lora_p_kernel<<<dim3(1024), dim3(256), 0, stream>>>(y, p_A, lap);
  gemm_kernel<2><<<dim3(512), dim3(256), 0, stream>>>(
      y, wpb, p_b, lap, p_B, use_lora, nullptr, nullptr, d_out);
}

// Round 8
// 384.054 us; speedup vs baseline: 1.1608x; 1.0243x over previous
//
#include <hip/hip_runtime.h>

typedef _Float16 f16;
typedef _Float16 f16x4 __attribute__((ext_vector_type(4)));
typedef _Float16 f16x8 __attribute__((ext_vector_type(8)));
typedef __fp16 hf2 __attribute__((ext_vector_type(2)));
typedef float f32x4 __attribute__((ext_vector_type(4)));

#define DEV static __device__ __forceinline__

DEV void gl_lds16(const void* g, void* l) {
  __builtin_amdgcn_global_load_lds(
      (const __attribute__((address_space(1))) void*)g,
      (__attribute__((address_space(3))) void*)l, 16, 0, 0);
}

DEV uint pkrtz(float a, float b) {
  hf2 h = __builtin_amdgcn_cvt_pkrtz(a, b);
  return __builtin_bit_cast(uint, h);
}

DEV f32x4 MFMA(f16x8 a, f16x8 b, f32x4 c) {
  return __builtin_amdgcn_mfma_f32_16x16x32_f16(a, b, c, 0, 0, 0);
}

// ---------------- 1) cast fp32 -> fp16 (x + 4 weights) ----------------
__global__ void cast_f16_kernel(const float* __restrict__ x,
                                const float* __restrict__ w0,
                                const float* __restrict__ w1,
                                const float* __restrict__ w2,
                                const float* __restrict__ w3,
                                f16* __restrict__ xb, f16* __restrict__ b0,
                                f16* __restrict__ b1, f16* __restrict__ b2,
                                f16* __restrict__ b3) {
  const int total4 = (8388608 + 4 * 4194304) / 4;
  for (int i = blockIdx.x * blockDim.x + threadIdx.x; i < total4;
       i += gridDim.x * blockDim.x) {
    int e = i << 2;
    const float* s; f16* d; int off;
    if (e < 8388608)        { s = x;  d = xb; off = e; }
    else if (e < 12582912)  { s = w0; d = b0; off = e - 8388608; }
    else if (e < 16777216)  { s = w1; d = b1; off = e - 12582912; }
    else if (e < 20971520)  { s = w2; d = b2; off = e - 16777216; }
    else                    { s = w3; d = b3; off = e - 20971520; }
    float4 v = *(const float4*)(s + off);
    f16x4 hv = {(f16)v.x, (f16)v.y, (f16)v.z, (f16)v.w};
    *(f16x4*)(d + off) = hv;
  }
}

// ---------------- 2a) la[nm][m][r] = x @ A_nm  (fp32, q/k/v) ----------------
__global__ __launch_bounds__(256) void lora_x_kernel(
    const float* __restrict__ x, const float* __restrict__ Aq,
    const float* __restrict__ Ak, const float* __restrict__ Av,
    float* __restrict__ la) {
  const int wave = threadIdx.x >> 6, lane = threadIdx.x & 63;
  const int m = blockIdx.x * 4 + wave;
  const float* xrow = x + (size_t)m * 2048;
  const float* As[3] = {Aq, Ak, Av};
  float acc[3][8] = {};
  for (int i = 0; i < 32; ++i) {
    int k = i * 64 + lane;
    float xv = xrow[k];
#pragma unroll
    for (int nm = 0; nm < 3; ++nm) {
      const float4* ap = (const float4*)(As[nm] + (size_t)k * 8);
      float4 a0 = ap[0], a1 = ap[1];
      acc[nm][0] += xv * a0.x; acc[nm][1] += xv * a0.y;
      acc[nm][2] += xv * a0.z; acc[nm][3] += xv * a0.w;
      acc[nm][4] += xv * a1.x; acc[nm][5] += xv * a1.y;
      acc[nm][6] += xv * a1.z; acc[nm][7] += xv * a1.w;
    }
  }
#pragma unroll
  for (int nm = 0; nm < 3; ++nm)
#pragma unroll
    for (int r = 0; r < 8; ++r) {
      float v = acc[nm][r];
#pragma unroll
      for (int off = 1; off < 64; off <<= 1) v += __shfl_xor(v, off);
      acc[nm][r] = v;
    }
  if (lane == 0) {
#pragma unroll
    for (int nm = 0; nm < 3; ++nm)
#pragma unroll
      for (int r = 0; r < 8; ++r)
        la[nm * 32768 + (size_t)m * 8 + r] = acc[nm][r];
  }
}

// ---------------- 2b) lap[m][r] = y @ p_A  (y = f16 attention output) -------
__global__ __launch_bounds__(256) void lora_p_kernel(
    const f16* __restrict__ y, const float* __restrict__ Ap,
    float* __restrict__ lap) {
  const int wave = threadIdx.x >> 6, lane = threadIdx.x & 63;
  const int m = blockIdx.x * 4 + wave;
  const f16* yrow = y + (size_t)m * 2048;
  float acc[8] = {};
  for (int i = 0; i < 4; ++i) {
    int k0 = i * 512 + lane * 8;
    f16x8 yv = *(const f16x8*)(yrow + k0);
#pragma unroll
    for (int j = 0; j < 8; ++j) {
      float xv = (float)yv[j];
      const float4* ap = (const float4*)(Ap + (size_t)(k0 + j) * 8);
      float4 a0 = ap[0], a1 = ap[1];
      acc[0] += xv * a0.x; acc[1] += xv * a0.y;
      acc[2] += xv * a0.z; acc[3] += xv * a0.w;
      acc[4] += xv * a1.x; acc[5] += xv * a1.y;
      acc[6] += xv * a1.z; acc[7] += xv * a1.w;
    }
  }
#pragma unroll
  for (int r = 0; r < 8; ++r) {
    float v = acc[r];
#pragma unroll
    for (int off = 1; off < 64; off <<= 1) v += __shfl_xor(v, off);
    acc[r] = v;
  }
  if (lane == 0) {
#pragma unroll
    for (int r = 0; r < 8; ++r) lap[(size_t)m * 8 + r] = acc[r];
  }
}

// ------- 3/6) MFMA GEMM, 8-phase-style counted-vmcnt pipeline -------
// BM=128, BN=256, BK=64; 512 thr (8 waves, 2Mx4N, 64x64/wave);
// triple-buffered LDS (3 x 48KB), stage 2 tiles ahead, vmcnt(6) boundaries.
// MODE 0: rope epilogue -> f16 [B,H,T,D] (q,k; tile = 2 heads)
// MODE 1: plain f16 [B,T,C] (v)
// MODE 2: fp32 [B,T,C] (p -> d_out)
template <int MODE>
__global__ __launch_bounds__(512, 1) void gemm_kernel(
    const f16* __restrict__ A, const f16* __restrict__ Bw,
    const float* __restrict__ bias, const float* __restrict__ la,
    const float* __restrict__ Bm, const int* __restrict__ use_lora,
    const float* __restrict__ cosT, const float* __restrict__ sinT,
    void* __restrict__ out) {
  extern __shared__ char smem[];
  const int tid = threadIdx.x;
  const int wave = tid >> 6, lane = tid & 63;
  const int lr = lane & 15, lg = lane >> 4;
  const int bm = (int)blockIdx.x >> 3, bn = (int)blockIdx.x & 7;
  const int m0 = bm << 7, n0 = bn << 8;
  const int wr = wave >> 2, wc = wave & 3;  // 2 x 4 wave grid, 64x64 each

  const char* Ab = (const char*)A;
  const char* Bb = (const char*)Bw;

  // staging: LDS linear dest (wave-uniform base), pre-swizzled global source
  auto stageA = [&](int kt, int bsel, int sw) {
    uint base = (uint)sw * 8192u + (uint)wave * 1024u;
    uint idx = base + (uint)lane * 16u;
    uint row = idx >> 7, cb = idx & 127u;
    uint c = cb ^ ((row & 7u) << 4);
    gl_lds16(Ab + (size_t)(m0 + row) * 4096 + (size_t)kt * 128 + c,
             smem + bsel * 49152 + base);
  };
  auto stageB = [&](int kt, int bsel, int sw) {
    uint base = (uint)sw * 8192u + (uint)wave * 1024u;
    uint idx = base + (uint)lane * 16u;
    uint row = idx >> 7, cb = idx & 127u;
    uint c = cb ^ ((row & 7u) << 4);
    gl_lds16(Bb + (size_t)(n0 + row) * 4096 + (size_t)kt * 128 + c,
             smem + bsel * 49152 + 16384 + base);
  };
  auto rdA = [&](int bsel, int ks, int mi) -> f16x8 {
    int row = wr * 64 + mi * 16 + lr;
    int c = (ks * 64 + lg * 16) ^ ((row & 7) << 4);
    return *(const f16x8*)(smem + bsel * 49152 + row * 128 + c);
  };
  auto rdB = [&](int bsel, int ks, int ni) -> f16x8 {
    int row = wc * 64 + ni * 16 + lr;
    int c = (ks * 64 + lg * 16) ^ ((row & 7) << 4);
    return *(const f16x8*)(smem + bsel * 49152 + 16384 + row * 128 + c);
  };

  f32x4 acc[4][4] = {};

  // prologue: stage tiles 0 and 1 (6 loads each)
#pragma unroll
  for (int sw = 0; sw < 2; ++sw) stageA(0, 0, sw);
#pragma unroll
  for (int sw = 0; sw < 4; ++sw) stageB(0, 0, sw);
#pragma unroll
  for (int sw = 0; sw < 2; ++sw) stageA(1, 1, sw);
#pragma unroll
  for (int sw = 0; sw < 4; ++sw) stageB(1, 1, sw);

  for (int kt = 0; kt < 32; ++kt) {
    const int cur = kt % 3;
    const int nxt = (kt + 2) % 3;
    const bool st = (kt + 2 < 32);
    // tile boundary: wait this tile's loads; allow next tile's 6 in flight
    if (kt == 31) asm volatile("s_waitcnt vmcnt(0)" ::: "memory");
    else         asm volatile("s_waitcnt vmcnt(6)" ::: "memory");
    __builtin_amdgcn_s_barrier();

    f16x8 a0, a1, a2, a3, b0, b1;
    // ---- phase 0: ks0, ni{0,1}; stage A of kt+2 ----
    a0 = rdA(cur, 0, 0); a1 = rdA(cur, 0, 1);
    a2 = rdA(cur, 0, 2); a3 = rdA(cur, 0, 3);
    b0 = rdB(cur, 0, 0); b1 = rdB(cur, 0, 1);
    if (st) { stageA(kt + 2, nxt, 0); stageA(kt + 2, nxt, 1); }
    __builtin_amdgcn_s_setprio(1);
    acc[0][0] = MFMA(a0, b0, acc[0][0]); acc[1][0] = MFMA(a1, b0, acc[1][0]);
    acc[2][0] = MFMA(a2, b0, acc[2][0]); acc[3][0] = MFMA(a3, b0, acc[3][0]);
    acc[0][1] = MFMA(a0, b1, acc[0][1]); acc[1][1] = MFMA(a1, b1, acc[1][1]);
    acc[2][1] = MFMA(a2, b1, acc[2][1]); acc[3][1] = MFMA(a3, b1, acc[3][1]);
    __builtin_amdgcn_s_setprio(0);
    __builtin_amdgcn_s_barrier();

    // ---- phase 1: ks0, ni{2,3}; stage B0,B1 of kt+2 ----
    b0 = rdB(cur, 0, 2); b1 = rdB(cur, 0, 3);
    if (st) { stageB(kt + 2, nxt, 0); stageB(kt + 2, nxt, 1); }
    __builtin_amdgcn_s_setprio(1);
    acc[0][2] = MFMA(a0, b0, acc[0][2]); acc[1][2] = MFMA(a1, b0, acc[1][2]);
    acc[2][2] = MFMA(a2, b0, acc[2][2]); acc[3][2] = MFMA(a3, b0, acc[3][2]);
    acc[0][3] = MFMA(a0, b1, acc[0][3]); acc[1][3] = MFMA(a1, b1, acc[1][3]);
    acc[2][3] = MFMA(a2, b1, acc[2][3]); acc[3][3] = MFMA(a3, b1, acc[3][3]);
    __builtin_amdgcn_s_setprio(0);
    __builtin_amdgcn_s_barrier();

    // ---- phase 2: ks1, ni{0,1}; stage B2,B3 of kt+2 ----
    a0 = rdA(cur, 1, 0); a1 = rdA(cur, 1, 1);
    a2 = rdA(cur, 1, 2); a3 = rdA(cur, 1, 3);
    b0 = rdB(cur, 1, 0); b1 = rdB(cur, 1, 1);
    if (st) { stageB(kt + 2, nxt, 2); stageB(kt + 2, nxt, 3); }
    __builtin_amdgcn_s_setprio(1);
    acc[0][0] = MFMA(a0, b0, acc[0][0]); acc[1][0] = MFMA(a1, b0, acc[1][0]);
    acc[2][0] = MFMA(a2, b0, acc[2][0]); acc[3][0] = MFMA(a3, b0, acc[3][0]);
    acc[0][1] = MFMA(a0, b1, acc[0][1]); acc[1][1] = MFMA(a1, b1, acc[1][1]);
    acc[2][1] = MFMA(a2, b1, acc[2][1]); acc[3][1] = MFMA(a3, b1, acc[3][1]);
    __builtin_amdgcn_s_setprio(0);
    __builtin_amdgcn_s_barrier();

    // ---- phase 3: ks1, ni{2,3}; no stage ----
    b0 = rdB(cur, 1, 2); b1 = rdB(cur, 1, 3);
    __builtin_amdgcn_s_setprio(1);
    acc[0][2] = MFMA(a0, b0, acc[0][2]); acc[1][2] = MFMA(a1, b0, acc[1][2]);
    acc[2][2] = MFMA(a2, b0, acc[2][2]); acc[3][2] = MFMA(a3, b0, acc[3][2]);
    acc[0][3] = MFMA(a0, b1, acc[0][3]); acc[1][3] = MFMA(a1, b1, acc[1][3]);
    acc[2][3] = MFMA(a2, b1, acc[2][3]); acc[3][3] = MFMA(a3, b1, acc[3][3]);
    __builtin_amdgcn_s_setprio(0);
  }
  __builtin_amdgcn_s_barrier();  // all reads done; smem reusable for staging

  const int ul = use_lora[0];
  float bv[4], bml[4][8];
#pragma unroll
  for (int ni = 0; ni < 4; ++ni) {
    int n = n0 + wc * 64 + ni * 16 + lr;
    bv[ni] = bias[n];
    if (ul) {
#pragma unroll
      for (int r = 0; r < 8; ++r) bml[ni][r] = Bm[r * 2048 + n];
    }
  }

#pragma unroll
  for (int mi = 0; mi < 4; ++mi) {
    const int mbase = m0 + wr * 64 + mi * 16 + lg * 4;
    float lar[4][8];
    if (ul) {
#pragma unroll
      for (int rg = 0; rg < 4; ++rg) {
        const float4* lp = (const float4*)(la + (size_t)(mbase + rg) * 8);
        float4 l0 = lp[0], l1 = lp[1];
        lar[rg][0] = l0.x; lar[rg][1] = l0.y; lar[rg][2] = l0.z; lar[rg][3] = l0.w;
        lar[rg][4] = l1.x; lar[rg][5] = l1.y; lar[rg][6] = l1.z; lar[rg][7] = l1.w;
      }
    }
#pragma unroll
    for (int ni = 0; ni < 4; ++ni) {
      const int n = n0 + wc * 64 + ni * 16 + lr;
#pragma unroll
      for (int rg = 0; rg < 4; ++rg) {
        float v = acc[mi][ni][rg] + bv[ni];
        if (ul) {
#pragma unroll
          for (int r = 0; r < 8; ++r) v += lar[rg][r] * bml[ni][r];
        }
        const int lrow = wr * 64 + mi * 16 + lg * 4 + rg;
        if (MODE == 0) {
          float pv = __shfl_xor(v, 1);  // RoPE partner column (lr parity)
          const int t = (mbase + rg) & 2047;
          const int d = n & 127;
          const int ci = t * 64 + (d >> 1);
          float cs = cosT[ci], sn = sinT[ci];
          float res = ((lane & 1) == 0) ? (v * cs - pv * sn)
                                        : (pv * sn + v * cs);
          int cbyte = ((wc * 64 + ni * 16 + lr) * 2) ^ ((lrow & 7) << 4);
          *(f16*)(smem + lrow * 512 + cbyte) = (f16)res;
        } else if (MODE == 1) {
          int cbyte = ((wc * 64 + ni * 16 + lr) * 2) ^ ((lrow & 7) << 4);
          *(f16*)(smem + lrow * 512 + cbyte) = (f16)v;
        } else {
          ((float*)out)[(size_t)(mbase + rg) * 2048 + n] = v;
        }
      }
    }
  }

  if (MODE < 2) {
    __builtin_amdgcn_s_barrier();
#pragma unroll
    for (int p = 0; p < 8; ++p) {
      int s = p * 8192 + tid * 16;
      int row = s >> 9, cb = s & 511;
      int c = cb ^ ((row & 7) << 4);
      uint4 val = *(const uint4*)(smem + row * 512 + c);
      if (MODE == 0) {
        const long b_ = (m0 + row) >> 11;
        const int tb = (m0 + row) & 2047;
        const int head = 2 * bn + (cb >> 8);
        char* dst = (char*)out + ((b_ * 16 + head) * 2048 + tb) * 256 + (cb & 255);
        *(uint4*)dst = val;
      } else {
        char* dst = (char*)out + ((long)(m0 + row) * 2048 + bn * 256) * 2 + cb;
        *(uint4*)dst = val;
      }
    }
  }
}

// ---------------- 4) v [B,T,H,D] -> vt [B,H,D,T] ----------------
__global__ void transpose_v_kernel(const ushort* __restrict__ vbi,
                                   ushort* __restrict__ vto) {
  __shared__ ushort tile[32][33];
  const int t0 = blockIdx.x << 5;
  const int d0 = blockIdx.y << 5;
  const int bh = blockIdx.z;
  const int b = bh >> 4, h = bh & 15;
  const int tx = threadIdx.x, ty = threadIdx.y;
  const ushort* src = vbi + ((size_t)(b * 2048 + t0)) * 2048 + h * 128 + d0;
#pragma unroll
  for (int i = 0; i < 4; ++i)
    tile[ty + 8 * i][tx] = src[(size_t)(ty + 8 * i) * 2048 + tx];
  __syncthreads();
  ushort* dst = vto + ((size_t)bh * 128 + d0) * 2048 + t0;
#pragma unroll
  for (int i = 0; i < 4; ++i)
    dst[(size_t)(ty + 8 * i) * 2048 + tx] = tile[tx][ty + 8 * i];
}

// ---------------- 5) causal flash attention (v2 + defer-max T13) -------------
__global__ __launch_bounds__(256, 2) void attn_kernel(
    const f16* __restrict__ qr, const f16* __restrict__ kr,
    const f16* __restrict__ vt, f16* __restrict__ y) {
  extern __shared__ char smem[];  // 2 x (K 16KB + V 16KB) = 64KB
  const int tid = threadIdx.x, wave = tid >> 6, lane = tid & 63;
  const int lr = lane & 15, lg = lane >> 4;
  const int qt = 15 - (int)blockIdx.x;  // longest blocks dispatch first
  const int q0 = qt << 7;
  const int h = blockIdx.y, b = blockIdx.z;
  const long bh = b * 16 + h;
  const int nt = 2 * qt + 2;

  const char* kbase = (const char*)kr + bh * 2048 * 256;
  const char* vbase = (const char*)vt + bh * 128 * 4096;

  f16x8 qf[2][4];
#pragma unroll
  for (int g = 0; g < 2; ++g) {
    const char* qb =
        (const char*)qr + (bh * 2048 + q0 + wave * 32 + g * 16 + lr) * 256;
#pragma unroll
    for (int ks = 0; ks < 4; ++ks)
      qf[g][ks] = *(const f16x8*)(qb + ks * 64 + lg * 16);
  }

  f32x4 o[2][8] = {};
  float mrow[2] = {-3e38f, -3e38f};
  float lsum[2] = {0.f, 0.f};
  const float SC2 = 0.12752551286084103f;  // (1/sqrt(128))*log2(e)

  auto STAGE = [&](int kv0, int bsel) {
    char* Ks = smem + bsel * 32768;
    char* Vs = Ks + 16384;
#pragma unroll
    for (int r = 0; r < 4; ++r) {
      uint s = (uint)(wave * 4 + r) * 1024 + (uint)lane * 16;
      uint rowk = s >> 8, ck = (s & 255u) ^ ((rowk & 7u) << 4);
      gl_lds16(kbase + (size_t)(kv0 + rowk) * 256 + ck,
               Ks + (wave * 4 + r) * 1024);
      uint rowv = s >> 7, cv = (s & 127u) ^ ((rowv & 7u) << 4);
      gl_lds16(vbase + (size_t)rowv * 4096 + kv0 * 2 + cv,
               Vs + (wave * 4 + r) * 1024);
    }
  };

  STAGE(0, 0);
  __syncthreads();

  for (int kt = 0; kt < nt; ++kt) {
    const int kv0 = kt << 6;
    if (kt + 1 < nt) STAGE((kt + 1) << 6, (kt + 1) & 1);
    const char* Ks = smem + (kt & 1) * 32768;
    const char* Vs = Ks + 16384;

    if (kv0 <= q0 + wave * 32 + 31) {
      f32x4 sa[2][4] = {};
      __builtin_amdgcn_s_setprio(1);
#pragma unroll
      for (int ks = 0; ks < 4; ++ks)
#pragma unroll
        for (int n = 0; n < 4; ++n) {
          int row = n * 16 + lr;
          int c = (ks * 64 + lg * 16) ^ ((row & 7) << 4);
          f16x8 kf = *(const f16x8*)(Ks + row * 256 + c);
          sa[0][n] = MFMA(kf, qf[0][ks], sa[0][n]);
          sa[1][n] = MFMA(kf, qf[1][ks], sa[1][n]);
        }
      __builtin_amdgcn_s_setprio(0);

      f16x8 pf[2][2];
#pragma unroll
      for (int g = 0; g < 2; ++g) {
        const int qgbase = q0 + wave * 32 + g * 16;
        float L[16];
        float pm = -3e38f;
        const bool dm = (kv0 + 63 > qgbase);
#pragma unroll
        for (int n = 0; n < 4; ++n)
#pragma unroll
          for (int rg = 0; rg < 4; ++rg) {
            float Lv = sa[g][n][rg] * SC2;
            if (dm && (kv0 + n * 16 + lg * 4 + rg > qgbase + lr)) Lv = -3e37f;
            L[n * 4 + rg] = Lv;
            pm = fmaxf(pm, Lv);
          }
        pm = fmaxf(pm, __shfl_xor(pm, 16));
        pm = fmaxf(pm, __shfl_xor(pm, 32));
        // T13 defer-max: rescale only when max drifted > 8 (log2 units)
        if (!__all(pm - mrow[g] <= 8.f)) {
          float mn = fmaxf(mrow[g], pm);
          float alpha = exp2f(mrow[g] - mn);
          mrow[g] = mn;
          lsum[g] *= alpha;
#pragma unroll
          for (int dt = 0; dt < 8; ++dt)
#pragma unroll
            for (int rg = 0; rg < 4; ++rg) o[g][dt][rg] *= alpha;
        }
        const float mn = mrow[g];
        float ps = 0.f;
#pragma unroll
        for (int i = 0; i < 16; ++i) {
          float p = exp2f(L[i] - mn);
          L[i] = p;
          ps += p;
        }
        ps += __shfl_xor(ps, 16);
        ps += __shfl_xor(ps, 32);
        lsum[g] += ps;

        // P -> B-fragment via in-register 4-lane word transpose
#pragma unroll
        for (int ks2 = 0; ks2 < 2; ++ks2) {
          uint w0 = pkrtz(L[8 * ks2 + 0], L[8 * ks2 + 1]);
          uint w1 = pkrtz(L[8 * ks2 + 2], L[8 * ks2 + 3]);
          uint w2 = pkrtz(L[8 * ks2 + 4], L[8 * ks2 + 5]);
          uint w3 = pkrtz(L[8 * ks2 + 6], L[8 * ks2 + 7]);
          int src1 = ((lg & 1) << 5) + lr;
          int src2 = src1 + 16;
          uint a0 = __shfl((int)w0, src1), a1 = __shfl((int)w1, src1);
          uint a2 = __shfl((int)w2, src1), a3 = __shfl((int)w3, src1);
          uint b0 = __shfl((int)w0, src2), b1 = __shfl((int)w1, src2);
          uint b2 = __shfl((int)w2, src2), b3 = __shfl((int)w3, src2);
          const bool hi = (lg >> 1) != 0;
          uint4 uu;
          uu.x = hi ? a2 : a0;
          uu.y = hi ? a3 : a1;
          uu.z = hi ? b2 : b0;
          uu.w = hi ? b3 : b1;
          pf[g][ks2] = __builtin_bit_cast(f16x8, uu);
        }
      }

#pragma unroll
      for (int ks2 = 0; ks2 < 2; ++ks2) {
        __builtin_amdgcn_s_setprio(1);
#pragma unroll
        for (int dt = 0; dt < 8; ++dt) {
          int drow = dt * 16 + lr;
          int c = (ks2 * 64 + lg * 16) ^ ((drow & 7) << 4);
          f16x8 vf = *(const f16x8*)(Vs + drow * 128 + c);
          o[0][dt] = MFMA(vf, pf[0][ks2], o[0][dt]);
          o[1][dt] = MFMA(vf, pf[1][ks2], o[1][dt]);
        }
        __builtin_amdgcn_s_setprio(0);
      }
    }
    __syncthreads();
  }

  // epilogue: normalize, stage 128x256B in LDS (swizzled), coalesced store
#pragma unroll
  for (int g = 0; g < 2; ++g) {
    const float inv = 1.f / lsum[g];
    const int row = wave * 32 + g * 16 + lr;
#pragma unroll
    for (int dt = 0; dt < 8; ++dt) {
      uint lo = pkrtz(o[g][dt][0] * inv, o[g][dt][1] * inv);
      uint hi2 = pkrtz(o[g][dt][2] * inv, o[g][dt][3] * inv);
      int c = (dt * 32 + lg * 8) ^ ((row & 7) << 4);
      uint2 w;
      w.x = lo;
      w.y = hi2;
      *(uint2*)(smem + row * 256 + c) = w;
    }
  }
  __syncthreads();
#pragma unroll
  for (int p = 0; p < 8; ++p) {
    int s = p * 4096 + tid * 16;
    int row = s >> 8, cb = s & 255;
    int c = cb ^ ((row & 7) << 4);
    char* dst =
        (char*)y + ((long)(b * 2048 + q0 + row) * 2048 + h * 128) * 2 + cb;
    *(uint4*)dst = *(const uint4*)(smem + row * 256 + c);
  }
}

// ---------------- launch ----------------
extern "C" void kernel_launch(void* const* d_in, const int* in_sizes, int n_in,
                              void* d_out, int out_size, void* d_ws,
                              size_t ws_size, hipStream_t stream) {
  (void)in_sizes; (void)n_in; (void)out_size; (void)ws_size;
  const float* x   = (const float*)d_in[0];
  const float* q_w = (const float*)d_in[1];
  const float* q_b = (const float*)d_in[2];
  const float* q_A = (const float*)d_in[3];
  const float* q_B = (const float*)d_in[4];
  const float* k_w = (const float*)d_in[5];
  const float* k_b = (const float*)d_in[6];
  const float* k_A = (const float*)d_in[7];
  const float* k_B = (const float*)d_in[8];
  const float* v_w = (const float*)d_in[9];
  const float* v_b = (const float*)d_in[10];
  const float* v_A = (const float*)d_in[11];
  const float* v_B = (const float*)d_in[12];
  const float* p_w = (const float*)d_in[13];
  const float* p_b = (const float*)d_in[14];
  const float* p_A = (const float*)d_in[15];
  const float* p_B = (const float*)d_in[16];
  const float* cosT = (const float*)d_in[17];
  const float* sinT = (const float*)d_in[18];
  const int* use_lora = (const int*)d_in[20];  // mask (19) implicit: causal

  char* ws = (char*)d_ws;
  f16* xb  = (f16*)(ws);                    // 16.78 MB ; later reused as vt
  f16* wqb = (f16*)(ws + 16777216);
  f16* wkb = (f16*)(ws + 25165824);
  f16* wvb = (f16*)(ws + 33554432);
  f16* wpb = (f16*)(ws + 41943040);
  float* la = (float*)(ws + 50331648);      // [4][4096][8] fp32
  f16* qr  = (f16*)(ws + 50855936);         // [B,H,T,D]
  f16* kr  = (f16*)(ws + 67633152);         // [B,H,T,D]
  f16* vb  = (f16*)(ws + 84410368);         // [B,T,C] ; later reused as y
  f16* vt  = (f16*)(ws);                    // [B,H,D,T] aliases xb (xb dead)
  f16* y   = vb;                            // aliases vb (vb dead after transpose)
  float* lap = la + 98304;                  // p-slot, filled from y post-attn

  cast_f16_kernel<<<dim3(2048), dim3(256), 0, stream>>>(
      x, q_w, k_w, v_w, p_w, xb, wqb, wkb, wvb, wpb);
  lora_x_kernel<<<dim3(1024), dim3(256), 0, stream>>>(x, q_A, k_A, v_A, la);
  gemm_kernel<0><<<dim3(256), dim3(512), 147456, stream>>>(
      xb, wqb, q_b, la, q_B, use_lora, cosT, sinT, (void*)qr);
  gemm_kernel<0><<<dim3(256), dim3(512), 147456, stream>>>(
      xb, wkb, k_b, la + 32768, k_B, use_lora, cosT, sinT, (void*)kr);
  gemm_kernel<1><<<dim3(256), dim3(512), 147456, stream>>>(
      xb, wvb, v_b, la + 65536, v_B, use_lora, nullptr, nullptr, (void*)vb);
  transpose_v_kernel<<<dim3(64, 4, 32), dim3(32, 8), 0, stream>>>(
      (const ushort*)vb, (ushort*)vt);
  attn_kernel<<<dim3(16, 16, 2), dim3(256), 65536, stream>>>(qr, kr, vt, y);
  lora_p_kernel<<<dim3(1024), dim3(256), 0, stream>>>(y, p_A, lap);
  gemm_kernel<2><<<dim3(256), dim3(512), 147456, stream>>>(
      y, wpb, p_b, lap, p_B, use_lora, nullptr, nullptr, d_out);
}